// Round 1
// baseline (530.198 us; speedup 1.0000x reference)
//
#include <hip/hip_runtime.h>
#include <math.h>

#define H2 128
#define W2 128
#define WF 65          // W2/2 + 1
#define BC 1024        // B*C = 8*128
#define NPOS (8*128*65)  // B * H2 * WF = 66560
#define LAMBD 0.01f

__device__ __forceinline__ int brev7(int n) { return (int)(__brev((unsigned)n) >> 25); }

// ---------------- Pass 0: 2x2 maxpool + avgpool ----------------
__global__ void pool_kernel(const float* __restrict__ x, float* __restrict__ y, int n) {
    int idx = blockIdx.x * blockDim.x + threadIdx.x;
    if (idx >= n) return;
    int j  = idx & (W2 - 1);
    int t  = idx >> 7;         // /128
    int i  = t & (H2 - 1);
    int bc = t >> 7;
    const float* p = x + (((size_t)bc * 256 + 2 * i) * 256 + 2 * j);
    float a = p[0], b = p[1], c = p[256], d = p[257];
    float mx = fmaxf(fmaxf(a, b), fmaxf(c, d));
    y[idx] = mx + 0.25f * (a + b + c + d);
}

// ---------------- Pass 1: row rfft (128 real -> 65 complex), fwd ortho scale 1/128 ----------------
__global__ __launch_bounds__(64) void rowfft_kernel(const float* __restrict__ y, float2* __restrict__ f) {
    __shared__ float re[128], im[128], twr[64], twi[64];
    int tid = threadIdx.x;
    int row = blockIdx.x;  // 0 .. BC*H2-1
    const float* src = y + (size_t)row * 128;
    float sv, cv;
    sincosf(-6.283185307179586f * (float)tid / 128.0f, &sv, &cv);
    twr[tid] = cv; twi[tid] = sv;
    int n0 = tid, n1 = tid + 64;
    re[brev7(n0)] = src[n0]; im[brev7(n0)] = 0.f;
    re[brev7(n1)] = src[n1]; im[brev7(n1)] = 0.f;
    __syncthreads();
    for (int s = 1; s <= 7; ++s) {
        int half = 1 << (s - 1);
        int j = tid & (half - 1);
        int g = tid >> (s - 1);
        int i0 = (g << s) + j;
        int i1 = i0 + half;
        float wr = twr[j << (7 - s)], wi = twi[j << (7 - s)];
        float ar = re[i0], ai = im[i0];
        float br = re[i1], bi = im[i1];
        float tr = br * wr - bi * wi;
        float ti = br * wi + bi * wr;
        re[i0] = ar + tr; im[i0] = ai + ti;
        re[i1] = ar - tr; im[i1] = ai - ti;
        __syncthreads();
    }
    const float scale = 1.0f / 128.0f;
    float2* dst = f + (size_t)row * WF;
    dst[tid] = make_float2(re[tid] * scale, im[tid] * scale);
    if (tid == 0) dst[64] = make_float2(re[64] * scale, im[64] * scale);
}

// ---------------- Pass 2/4: column FFT along H (complex, in-place), 8 cols per block ----------------
template <int SIGN, bool SCALE>
__global__ __launch_bounds__(256) void colfft_kernel(float2* __restrict__ f) {
    __shared__ float re[128 * 8], im[128 * 8], twr[64], twi[64];
    int tid = threadIdx.x;
    int bc = blockIdx.x;
    int k0 = blockIdx.y * 8;
    int ncol = WF - k0; if (ncol > 8) ncol = 8;
    if (tid < 64) {
        float sv, cv;
        sincosf((float)SIGN * 6.283185307179586f * (float)tid / 128.0f, &sv, &cv);
        twr[tid] = cv; twi[tid] = sv;
    }
    float2* base = f + ((size_t)bc * H2) * WF + k0;
    for (int l = tid; l < 128 * 8; l += 256) {
        int h = l >> 3, c = l & 7;
        int p = brev7(h) * 8 + c;
        if (c < ncol) {
            float2 v = base[(size_t)h * WF + c];
            re[p] = v.x; im[p] = v.y;
        } else {
            re[p] = 0.f; im[p] = 0.f;
        }
    }
    __syncthreads();
    for (int s = 1; s <= 7; ++s) {
        int half = 1 << (s - 1);
        for (int w = tid; w < 512; w += 256) {
            int c = w & 7;
            int t = w >> 3;
            int j = t & (half - 1);
            int g = t >> (s - 1);
            int i0 = (g << s) + j;
            int i1 = i0 + half;
            float wr = twr[j << (7 - s)], wi = twi[j << (7 - s)];
            int a0 = i0 * 8 + c, a1 = i1 * 8 + c;
            float ar = re[a0], ai = im[a0];
            float br = re[a1], bi = im[a1];
            float tr = br * wr - bi * wi;
            float ti = br * wi + bi * wr;
            re[a0] = ar + tr; im[a0] = ai + ti;
            re[a1] = ar - tr; im[a1] = ai - ti;
        }
        __syncthreads();
    }
    const float scale = SCALE ? (1.0f / 128.0f) : 1.0f;
    for (int l = tid; l < 128 * 8; l += 256) {
        int h = l >> 3, c = l & 7;
        if (c < ncol) {
            base[(size_t)h * WF + c] = make_float2(re[h * 8 + c] * scale, im[h * 8 + c] * scale);
        }
    }
}

// ---------------- Pass 3: block-diagonal complex MLP + softshrink + spectral gating, in-place ----------------
__global__ __launch_bounds__(256) void gating_kernel(float2* __restrict__ f,
                                                     const float* __restrict__ w1, const float* __restrict__ b1,
                                                     const float* __restrict__ w2, const float* __restrict__ b2) {
    __shared__ float s_w1r[256], s_w1i[256], s_w2r[256], s_w2i[256];
    __shared__ float s_b1r[16], s_b1i[16], s_b2r[16], s_b2i[16];
    int k = blockIdx.y;
    int tid = threadIdx.x;
    s_w1r[tid] = w1[(0 * 8 + k) * 256 + tid];
    s_w1i[tid] = w1[(1 * 8 + k) * 256 + tid];
    s_w2r[tid] = w2[(0 * 8 + k) * 256 + tid];
    s_w2i[tid] = w2[(1 * 8 + k) * 256 + tid];
    if (tid < 16) {
        s_b1r[tid] = b1[(0 * 8 + k) * 16 + tid];
        s_b1i[tid] = b1[(1 * 8 + k) * 16 + tid];
        s_b2r[tid] = b2[(0 * 8 + k) * 16 + tid];
        s_b2i[tid] = b2[(1 * 8 + k) * 16 + tid];
    }
    __syncthreads();
    int pos = blockIdx.x * 256 + tid;
    if (pos >= NPOS) return;
    int b  = pos / (H2 * WF);
    int hw = pos - b * (H2 * WF);
    size_t base = ((size_t)(b * 128 + k * 16)) * (size_t)(H2 * WF) + hw;
    const size_t cstride = H2 * WF;  // 8320
    float vr[16], vi[16], o1r[16], o1i[16];
    #pragma unroll
    for (int i = 0; i < 16; ++i) {
        float2 v = f[base + (size_t)i * cstride];
        vr[i] = v.x; vi[i] = v.y;
    }
    #pragma unroll
    for (int o = 0; o < 16; ++o) { o1r[o] = s_b1r[o]; o1i[o] = s_b1i[o]; }
    #pragma unroll
    for (int i = 0; i < 16; ++i) {
        #pragma unroll
        for (int o = 0; o < 16; ++o) {
            float wr = s_w1r[i * 16 + o], wi = s_w1i[i * 16 + o];
            o1r[o] += vr[i] * wr - vi[i] * wi;
            o1i[o] += vi[i] * wr + vr[i] * wi;
        }
    }
    #pragma unroll
    for (int o = 0; o < 16; ++o) {
        float ar = s_b2r[o], ai = s_b2i[o];
        #pragma unroll
        for (int i = 0; i < 16; ++i) {
            float wr = s_w2r[i * 16 + o], wi = s_w2i[i * 16 + o];
            ar += o1r[i] * wr - o1i[i] * wi;
            ai += o1i[i] * wr + o1r[i] * wi;
        }
        // softshrink(lambda=0.01)
        ar = copysignf(fmaxf(fabsf(ar) - LAMBD, 0.0f), ar);
        ai = copysignf(fmaxf(fabsf(ai) - LAMBD, 0.0f), ai);
        // z = g * f
        float zr = ar * vr[o] - ai * vi[o];
        float zi = ar * vi[o] + ai * vr[o];
        f[base + (size_t)o * cstride] = make_float2(zr, zi);
    }
}

// ---------------- Pass 5: row irfft (65 complex -> 128 real) + residual add into y ----------------
__global__ __launch_bounds__(64) void rowifft_kernel(const float2* __restrict__ z, float* __restrict__ y) {
    __shared__ float re[128], im[128], twr[64], twi[64];
    int tid = threadIdx.x;
    int row = blockIdx.x;
    const float2* src = z + (size_t)row * WF;
    float sv, cv;
    sincosf(6.283185307179586f * (float)tid / 128.0f, &sv, &cv);
    twr[tid] = cv; twi[tid] = sv;
    {
        float2 v = src[tid];
        int p = brev7(tid);
        re[p] = v.x; im[p] = v.y;
        int n1 = tid + 64;
        float2 u = (tid == 0) ? src[64] : src[64 - tid];
        float ui = (tid == 0) ? u.y : -u.y;  // conj for mirrored bins
        int p1 = brev7(n1);
        re[p1] = u.x; im[p1] = ui;
    }
    __syncthreads();
    for (int s = 1; s <= 7; ++s) {
        int half = 1 << (s - 1);
        int j = tid & (half - 1);
        int g = tid >> (s - 1);
        int i0 = (g << s) + j;
        int i1 = i0 + half;
        float wr = twr[j << (7 - s)], wi = twi[j << (7 - s)];
        float ar = re[i0], ai = im[i0];
        float br = re[i1], bi = im[i1];
        float tr = br * wr - bi * wi;
        float ti = br * wi + bi * wr;
        re[i0] = ar + tr; im[i0] = ai + ti;
        re[i1] = ar - tr; im[i1] = ai - ti;
        __syncthreads();
    }
    float* dst = y + (size_t)row * 128;
    dst[tid]      += re[tid];        // residual: s = irfft + y (in-place on y)
    dst[tid + 64] += re[tid + 64];
}

// ---------------- Pass 6: bilinear 2x upsample (half-pixel, clamped) + bias x ----------------
__global__ void upsample_kernel(const float* __restrict__ s, const float* __restrict__ x,
                                float* __restrict__ out, int n) {
    int idx = blockIdx.x * blockDim.x + threadIdx.x;
    if (idx >= n) return;
    int J  = idx & 255;
    int t  = idx >> 8;
    int I  = t & 255;
    int bc = t >> 8;
    float syf = (float)I * 0.5f - 0.25f;
    float sxf = (float)J * 0.5f - 0.25f;
    int y0 = (int)floorf(syf); float fy = syf - (float)y0;
    int x0 = (int)floorf(sxf); float fx = sxf - (float)x0;
    int y1 = y0 + 1; if (y1 > 127) y1 = 127; if (y0 < 0) y0 = 0;
    int x1 = x0 + 1; if (x1 > 127) x1 = 127; if (x0 < 0) x0 = 0;
    const float* sp = s + (size_t)bc * (128 * 128);
    float v00 = sp[y0 * 128 + x0], v01 = sp[y0 * 128 + x1];
    float v10 = sp[y1 * 128 + x0], v11 = sp[y1 * 128 + x1];
    float v0 = v00 + fx * (v01 - v00);
    float v1 = v10 + fx * (v11 - v10);
    out[idx] = v0 + fy * (v1 - v0) + x[idx];
}

extern "C" void kernel_launch(void* const* d_in, const int* in_sizes, int n_in,
                              void* d_out, int out_size, void* d_ws, size_t ws_size,
                              hipStream_t stream) {
    const float* x  = (const float*)d_in[0];
    const float* w1 = (const float*)d_in[1];
    const float* b1 = (const float*)d_in[2];
    const float* w2 = (const float*)d_in[3];
    const float* b2 = (const float*)d_in[4];
    float*  out = (float*)d_out;
    float*  y   = (float*)d_ws;      // 16,777,216 floats = 64 MB (pooled image, then s = irfft + y)
    float2* f   = (float2*)d_out;    // 8,519,680 float2 = 68 MB scratch inside d_out (dead before final write)

    int nPool = BC * H2 * W2;
    pool_kernel<<<(nPool + 255) / 256, 256, 0, stream>>>(x, y, nPool);
    rowfft_kernel<<<BC * H2, 64, 0, stream>>>(y, f);
    colfft_kernel<-1, false><<<dim3(BC, 9), 256, 0, stream>>>(f);
    gating_kernel<<<dim3((NPOS + 255) / 256, 8), 256, 0, stream>>>(f, w1, b1, w2, b2);
    colfft_kernel<1, true><<<dim3(BC, 9), 256, 0, stream>>>(f);
    rowifft_kernel<<<BC * H2, 64, 0, stream>>>(f, y);
    int nOut = BC * 256 * 256;
    upsample_kernel<<<(nOut + 255) / 256, 256, 0, stream>>>(y, x, out, nOut);
}

// Round 2
// 460.568 us; speedup vs baseline: 1.1512x; 1.1512x over previous
//
#include <hip/hip_runtime.h>
#include <math.h>

#define H2 128
#define W2 128
#define WF 65          // W2/2 + 1
#define BC 1024        // B*C = 8*128
#define LAMBD 0.01f
#define LPAD 33        // LDS row pad for fused spectral kernel

__device__ __forceinline__ int brev7(int n) { return (int)(__brev((unsigned)n) >> 25); }

// ---------------- Pass 0: fused 2x2 max+avg pool + row rfft (4 rows / block) ----------------
// reads x directly, writes pooled y (needed later for residual) and spectral rows f.
__global__ __launch_bounds__(256) void poolfft_kernel(const float* __restrict__ x,
                                                      float* __restrict__ y,
                                                      float2* __restrict__ f) {
    __shared__ float re[4][128], im[4][128], twr[64], twi[64];
    int tid = threadIdx.x;
    int rw = tid >> 6;        // wave id = row slot
    int lane = tid & 63;
    if (tid < 64) {
        float sv, cv;
        sincosf(-6.283185307179586f * (float)tid / 128.0f, &sv, &cv);
        twr[tid] = cv; twi[tid] = sv;
    }
    int row = blockIdx.x * 4 + rw;            // 0 .. BC*H2-1
    int i  = row & (H2 - 1);
    int bc = row >> 7;
    // pool: x rows 2i, 2i+1, cols 4*lane..4*lane+3 -> pooled cols 2*lane, 2*lane+1
    const float* p0 = x + ((size_t)bc * 256 + 2 * i) * 256 + 4 * lane;
    float4 a = *(const float4*)p0;
    float4 b = *(const float4*)(p0 + 256);
    float v0 = fmaxf(fmaxf(a.x, a.y), fmaxf(b.x, b.y)) + 0.25f * (a.x + a.y + b.x + b.y);
    float v1 = fmaxf(fmaxf(a.z, a.w), fmaxf(b.z, b.w)) + 0.25f * (a.z + a.w + b.z + b.w);
    *(float2*)(y + (size_t)row * 128 + 2 * lane) = make_float2(v0, v1);
    int b0 = brev7(2 * lane), b1i = brev7(2 * lane + 1);
    re[rw][b0] = v0; im[rw][b0] = 0.f;
    re[rw][b1i] = v1; im[rw][b1i] = 0.f;
    __syncthreads();
    for (int s = 1; s <= 7; ++s) {
        int half = 1 << (s - 1);
        int j = lane & (half - 1);
        int g = lane >> (s - 1);
        int i0 = (g << s) + j;
        int i1 = i0 + half;
        float wr = twr[j << (7 - s)], wi = twi[j << (7 - s)];
        float ar = re[rw][i0], ai = im[rw][i0];
        float br = re[rw][i1], bi = im[rw][i1];
        float tr = br * wr - bi * wi;
        float ti = br * wi + bi * wr;
        re[rw][i0] = ar + tr; im[rw][i0] = ai + ti;
        re[rw][i1] = ar - tr; im[rw][i1] = ai - ti;
        __syncthreads();
    }
    const float scale = 1.0f / 128.0f;   // full ortho fwd scale 1/sqrt(128*128)
    float2* dst = f + (size_t)row * WF;
    dst[lane] = make_float2(re[rw][lane] * scale, im[rw][lane] * scale);
    if (lane == 0) dst[64] = make_float2(re[rw][64] * scale, im[rw][64] * scale);
}

// ---------------- Pass 1: fused column FFT fwd + gating MLP + column FFT inv ----------------
// One block: (b, k, w-pair). 16 channels x 128 H x 2 W columns in LDS.
__global__ __launch_bounds__(256) void specfused_kernel(float2* __restrict__ f,
                                                        const float* __restrict__ w1, const float* __restrict__ b1,
                                                        const float* __restrict__ w2, const float* __restrict__ b2) {
    __shared__ float re[128 * LPAD], im[128 * LPAD];
    __shared__ float twr[64], twi[64];
    __shared__ float s_w1r[256], s_w1i[256], s_w2r[256], s_w2i[256];
    __shared__ float s_b1r[16], s_b1i[16], s_b2r[16], s_b2i[16];
    int tid = threadIdx.x;
    int wg = blockIdx.x;   // 0..32 (w pairs)
    int k  = blockIdx.y;   // 0..7
    int bb = blockIdx.z;   // 0..7
    int ncol = (wg == 32) ? 1 : 2;
    if (tid < 64) {
        float sv, cv;
        sincosf(-6.283185307179586f * (float)tid / 128.0f, &sv, &cv);
        twr[tid] = cv; twi[tid] = sv;
    }
    s_w1r[tid] = w1[(0 * 8 + k) * 256 + tid];
    s_w1i[tid] = w1[(1 * 8 + k) * 256 + tid];
    s_w2r[tid] = w2[(0 * 8 + k) * 256 + tid];
    s_w2i[tid] = w2[(1 * 8 + k) * 256 + tid];
    if (tid < 16) {
        s_b1r[tid] = b1[(0 * 8 + k) * 16 + tid];
        s_b1i[tid] = b1[(1 * 8 + k) * 16 + tid];
        s_b2r[tid] = b2[(0 * 8 + k) * 16 + tid];
        s_b2i[tid] = b2[(1 * 8 + k) * 16 + tid];
    }
    const size_t cstride = (size_t)H2 * WF;  // 8320 float2 per channel plane
    float2* base = f + ((size_t)(bb * 128 + k * 16)) * cstride + (size_t)(wg * 2);
    // load 16c x 128h x ncol into LDS at bit-reversed h
    for (int it = 0; it < 8; ++it) {
        int u = tid + it * 256;       // 0..2047
        int c = u >> 7, h = u & 127;
        int hb = brev7(h);
        const float2* p = base + (size_t)c * cstride + (size_t)h * WF;
        float2 q0 = p[0];
        float2 q1 = (ncol > 1) ? p[1] : make_float2(0.f, 0.f);
        int l = hb * LPAD + 2 * c;
        re[l]     = q0.x; im[l]     = q0.y;
        re[l + 1] = q1.x; im[l + 1] = q1.y;
    }
    __syncthreads();
    // forward DIT (bit-reversed in -> natural out)
    for (int s = 1; s <= 7; ++s) {
        int half = 1 << (s - 1);
        for (int u = tid; u < 2048; u += 256) {
            int cw = u & 31;
            int t  = u >> 5;            // 0..63 butterfly index
            int j = t & (half - 1);
            int g = t >> (s - 1);
            int i0 = (g << s) + j;
            int i1 = i0 + half;
            float wr = twr[j << (7 - s)], wi = twi[j << (7 - s)];
            int a0 = i0 * LPAD + cw, a1 = i1 * LPAD + cw;
            float ar = re[a0], ai = im[a0];
            float br = re[a1], bi = im[a1];
            float tr = br * wr - bi * wi;
            float ti = br * wi + bi * wr;
            re[a0] = ar + tr; im[a0] = ai + ti;
            re[a1] = ar - tr; im[a1] = ai - ti;
        }
        __syncthreads();
    }
    // gating MLP: one (h, w) position per thread
    {
        int h = tid >> 1, w = tid & 1;
        int lb = h * LPAD + w;
        float vr[16], vi[16], o1r[16], o1i[16];
        #pragma unroll
        for (int c = 0; c < 16; ++c) { vr[c] = re[lb + 2 * c]; vi[c] = im[lb + 2 * c]; }
        #pragma unroll
        for (int o = 0; o < 16; ++o) { o1r[o] = s_b1r[o]; o1i[o] = s_b1i[o]; }
        #pragma unroll
        for (int c = 0; c < 16; ++c) {
            #pragma unroll
            for (int o = 0; o < 16; ++o) {
                float wr = s_w1r[c * 16 + o], wi = s_w1i[c * 16 + o];
                o1r[o] += vr[c] * wr - vi[c] * wi;
                o1i[o] += vi[c] * wr + vr[c] * wi;
            }
        }
        __syncthreads();  // all reads done before writes below
        #pragma unroll
        for (int o = 0; o < 16; ++o) {
            float ar = s_b2r[o], ai = s_b2i[o];
            #pragma unroll
            for (int c = 0; c < 16; ++c) {
                float wr = s_w2r[c * 16 + o], wi = s_w2i[c * 16 + o];
                ar += o1r[c] * wr - o1i[c] * wi;
                ai += o1i[c] * wr + o1r[c] * wi;
            }
            ar = copysignf(fmaxf(fabsf(ar) - LAMBD, 0.0f), ar);
            ai = copysignf(fmaxf(fabsf(ai) - LAMBD, 0.0f), ai);
            float zr = ar * vr[o] - ai * vi[o];
            float zi = ar * vi[o] + ai * vr[o];
            re[lb + 2 * o] = zr;
            im[lb + 2 * o] = zi;
        }
    }
    __syncthreads();
    // inverse DIF (natural in -> bit-reversed out), conj twiddles
    for (int s = 7; s >= 1; --s) {
        int half = 1 << (s - 1);
        for (int u = tid; u < 2048; u += 256) {
            int cw = u & 31;
            int t  = u >> 5;
            int j = t & (half - 1);
            int g = t >> (s - 1);
            int i0 = (g << s) + j;
            int i1 = i0 + half;
            float wr = twr[j << (7 - s)], wi = twi[j << (7 - s)];  // conj applied below
            int a0 = i0 * LPAD + cw, a1 = i1 * LPAD + cw;
            float ar = re[a0], ai = im[a0];
            float br = re[a1], bi = im[a1];
            float dr = ar - br, di = ai - bi;
            re[a0] = ar + br; im[a0] = ai + bi;
            re[a1] = dr * wr + di * wi;   // (dr + i di) * (wr - i wi)^* = *(wr, -wi) conj
            im[a1] = di * wr - dr * wi;
        }
        __syncthreads();
    }
    // store: natural h comes from bit-reversed LDS slot; inverse scale 1/128
    const float scale = 1.0f / 128.0f;
    for (int it = 0; it < 8; ++it) {
        int u = tid + it * 256;
        int c = u >> 7, h = u & 127;
        int hb = brev7(h);
        float2* p = base + (size_t)c * cstride + (size_t)h * WF;
        int l = hb * LPAD + 2 * c;
        p[0] = make_float2(re[l] * scale, im[l] * scale);
        if (ncol > 1) p[1] = make_float2(re[l + 1] * scale, im[l + 1] * scale);
    }
}

// ---------------- Pass 2: row irfft + residual add into y (4 rows / block) ----------------
__global__ __launch_bounds__(256) void rowifft_kernel(const float2* __restrict__ z, float* __restrict__ y) {
    __shared__ float re[4][128], im[4][128], twr[64], twi[64];
    int tid = threadIdx.x;
    int rw = tid >> 6;
    int lane = tid & 63;
    if (tid < 64) {
        float sv, cv;
        sincosf(6.283185307179586f * (float)tid / 128.0f, &sv, &cv);
        twr[tid] = cv; twi[tid] = sv;
    }
    int row = blockIdx.x * 4 + rw;
    const float2* src = z + (size_t)row * WF;
    {
        float2 v = src[lane];
        int p = brev7(lane);
        re[rw][p] = v.x; im[rw][p] = v.y;
        int n1 = lane + 64;
        float2 u = (lane == 0) ? src[64] : src[64 - lane];
        float ui = (lane == 0) ? u.y : -u.y;  // Hermitian mirror
        int p1 = brev7(n1);
        re[rw][p1] = u.x; im[rw][p1] = ui;
    }
    __syncthreads();
    for (int s = 1; s <= 7; ++s) {
        int half = 1 << (s - 1);
        int j = lane & (half - 1);
        int g = lane >> (s - 1);
        int i0 = (g << s) + j;
        int i1 = i0 + half;
        float wr = twr[j << (7 - s)], wi = twi[j << (7 - s)];
        float ar = re[rw][i0], ai = im[rw][i0];
        float br = re[rw][i1], bi = im[rw][i1];
        float tr = br * wr - bi * wi;
        float ti = br * wi + bi * wr;
        re[rw][i0] = ar + tr; im[rw][i0] = ai + ti;
        re[rw][i1] = ar - tr; im[rw][i1] = ai - ti;
        __syncthreads();
    }
    float* dst = y + (size_t)row * 128;
    dst[lane]      += re[rw][lane];
    dst[lane + 64] += re[rw][lane + 64];
}

// ---------------- Pass 3: bilinear 2x upsample + bias x, 4 outputs / thread ----------------
__global__ __launch_bounds__(256) void upsample_kernel(const float* __restrict__ s, const float* __restrict__ x,
                                                       float* __restrict__ out) {
    int t4 = blockIdx.x * blockDim.x + threadIdx.x;  // one thread = 4 consecutive output cols
    int tJ = t4 & 63;          // output col group: J = 4*tJ
    int r  = t4 >> 6;
    int I  = r & 255;
    int bc = r >> 8;
    float syf = (float)I * 0.5f - 0.25f;
    int y0 = (int)floorf(syf);
    float fy = syf - (float)y0;
    int y1 = y0 + 1; if (y1 > 127) y1 = 127; if (y0 < 0) y0 = 0;
    int u = 2 * tJ;
    int cm1 = u - 1; if (cm1 < 0) cm1 = 0;
    int cp1 = u + 1; if (cp1 > 127) cp1 = 127;
    int cp2 = u + 2; if (cp2 > 127) cp2 = 127;
    const float* sp = s + (size_t)bc * (128 * 128);
    const float* r0p = sp + y0 * 128;
    const float* r1p = sp + y1 * 128;
    float am1 = r0p[cm1], a0 = r0p[u], ap1 = r0p[cp1], ap2 = r0p[cp2];
    float bm1 = r1p[cm1], b0 = r1p[u], bp1 = r1p[cp1], bp2 = r1p[cp2];
    float rm1 = am1 + fy * (bm1 - am1);
    float rr0 = a0  + fy * (b0  - a0);
    float rp1 = ap1 + fy * (bp1 - ap1);
    float rp2 = ap2 + fy * (bp2 - ap2);
    float4 xv = *(const float4*)(x + (size_t)t4 * 4);
    float4 o;
    o.x = rm1 + 0.75f * (rr0 - rm1) + xv.x;
    o.y = rr0 + 0.25f * (rp1 - rr0) + xv.y;
    o.z = rr0 + 0.75f * (rp1 - rr0) + xv.z;
    o.w = rp1 + 0.25f * (rp2 - rp1) + xv.w;
    *(float4*)(out + (size_t)t4 * 4) = o;
}

extern "C" void kernel_launch(void* const* d_in, const int* in_sizes, int n_in,
                              void* d_out, int out_size, void* d_ws, size_t ws_size,
                              hipStream_t stream) {
    const float* x  = (const float*)d_in[0];
    const float* w1 = (const float*)d_in[1];
    const float* b1 = (const float*)d_in[2];
    const float* w2 = (const float*)d_in[3];
    const float* b2 = (const float*)d_in[4];
    float*  out = (float*)d_out;
    float*  y   = (float*)d_ws;      // 64 MB: pooled image, then s = irfft + y
    float2* f   = (float2*)d_out;    // 68 MB spectral scratch inside d_out (dead before final write)

    poolfft_kernel<<<BC * H2 / 4, 256, 0, stream>>>(x, y, f);
    specfused_kernel<<<dim3(33, 8, 8), 256, 0, stream>>>(f, w1, b1, w2, b2);
    rowifft_kernel<<<BC * H2 / 4, 256, 0, stream>>>(f, y);
    upsample_kernel<<<BC * 256 * 64 / 256, 256, 0, stream>>>(y, x, out);
}

// Round 3
// 396.962 us; speedup vs baseline: 1.3356x; 1.1602x over previous
//
#include <hip/hip_runtime.h>
#include <math.h>

#define H2 128
#define W2 128
#define WF 65
#define LAMBD 0.01f
#define LPAD 33

__device__ __forceinline__ int brev7(int n) { return (int)(__brev((unsigned)n) >> 25); }

// f2 layout (complex elems): f2[((bb*8 + k)*65 + w)*2048 + h*16 + c16]
// -> per (b,k,w) a contiguous 16 KB run over (h, c16).

// ---------------- Pass 0: pool + row rFFT -> transposed f2 ----------------
// block = (ht 0..63, k 0..7, bb 0..7): 16 channels x 2 h-rows = 32 length-128 row FFTs.
__global__ __launch_bounds__(256) void poolfft_kernel(const float* __restrict__ x,
                                                      float* __restrict__ y,
                                                      float2* __restrict__ f2) {
    __shared__ float re[32 * 129], im[32 * 129];
    __shared__ float twr[64], twi[64];
    int tid = threadIdx.x;
    int ht = blockIdx.x, k = blockIdx.y, bb = blockIdx.z;
    if (tid < 64) {
        float sv, cv;
        sincosf(-6.283185307179586f * (float)tid / 128.0f, &sv, &cv);
        twr[tid] = cv; twi[tid] = sv;
    }
    // load + pool: 32 rows (r = hh*16 + c16) x 64 quads; store at bit-reversed w
    for (int it = 0; it < 8; ++it) {
        int u = tid + it * 256;
        int r = u >> 6, q = u & 63;
        int c16 = r & 15, hh = r >> 4;
        int h = ht * 2 + hh;
        const float* p = x + (((size_t)(bb * 128 + k * 16 + c16) * 256 + 2 * h) * 256 + 4 * q);
        float4 a = *(const float4*)p;
        float4 b = *(const float4*)(p + 256);
        float v0 = fmaxf(fmaxf(a.x, a.y), fmaxf(b.x, b.y)) + 0.25f * (a.x + a.y + b.x + b.y);
        float v1 = fmaxf(fmaxf(a.z, a.w), fmaxf(b.z, b.w)) + 0.25f * (a.z + a.w + b.z + b.w);
        *(float2*)(y + ((size_t)(bb * 128 + k * 16 + c16) * 128 + h) * 128 + 2 * q) = make_float2(v0, v1);
        int p0 = brev7(2 * q);                 // brev7(2q+1) = p0 + 64
        re[r * 129 + p0] = v0;      im[r * 129 + p0] = 0.f;
        re[r * 129 + p0 + 64] = v1; im[r * 129 + p0 + 64] = 0.f;
    }
    __syncthreads();
    // forward DIT (bitrev in -> natural out)
    for (int s = 1; s <= 7; ++s) {
        int half = 1 << (s - 1);
        for (int it = 0; it < 8; ++it) {
            int u = tid + it * 256;
            int row = u >> 6, t = u & 63;
            int j = t & (half - 1), g = t >> (s - 1);
            int i0 = (g << s) + j, i1 = i0 + half;
            float wr = twr[j << (7 - s)], wi = twi[j << (7 - s)];
            int a0 = row * 129 + i0, a1 = row * 129 + i1;
            float ar = re[a0], ai = im[a0];
            float br = re[a1], bi = im[a1];
            float tr = br * wr - bi * wi, ti = br * wi + bi * wr;
            re[a0] = ar + tr; im[a0] = ai + ti;
            re[a1] = ar - tr; im[a1] = ai - ti;
        }
        __syncthreads();
    }
    const float scale = 1.0f / 128.0f;  // full forward ortho scale
    float2* dst = f2 + (size_t)((bb * 8 + k) * 65) * 2048 + ht * 32;
    for (int it = 0; it < 9; ++it) {
        int u = tid + it * 256;
        if (u < 2080) {
            int w = u >> 5, r = u & 31;
            dst[(size_t)w * 2048 + r] = make_float2(re[r * 129 + w] * scale, im[r * 129 + w] * scale);
        }
    }
}

// ---------------- Pass 1: column FFT fwd (DIF) + gating + column FFT inv (DIT) ----------------
// block = (wg 0..32, k, bb): 2 w-columns, 16 c, 128 h; all global access contiguous.
__global__ __launch_bounds__(256) void specfused_kernel(float2* __restrict__ f2,
        const float* __restrict__ w1, const float* __restrict__ b1,
        const float* __restrict__ w2, const float* __restrict__ b2) {
    __shared__ float re[128 * LPAD], im[128 * LPAD];
    __shared__ float twr[64], twi[64];
    __shared__ float s_w1r[256], s_w1i[256], s_w2r[256], s_w2i[256];
    __shared__ float s_b1r[16], s_b1i[16], s_b2r[16], s_b2i[16];
    int tid = threadIdx.x;
    int wg = blockIdx.x, k = blockIdx.y, bb = blockIdx.z;
    int ncol = (wg == 32) ? 1 : 2;
    if (tid < 64) {
        float sv, cv;
        sincosf(-6.283185307179586f * (float)tid / 128.0f, &sv, &cv);
        twr[tid] = cv; twi[tid] = sv;
    }
    s_w1r[tid] = w1[(0 * 8 + k) * 256 + tid];
    s_w1i[tid] = w1[(1 * 8 + k) * 256 + tid];
    s_w2r[tid] = w2[(0 * 8 + k) * 256 + tid];
    s_w2i[tid] = w2[(1 * 8 + k) * 256 + tid];
    if (tid < 16) {
        s_b1r[tid] = b1[(0 * 8 + k) * 16 + tid];
        s_b1i[tid] = b1[(1 * 8 + k) * 16 + tid];
        s_b2r[tid] = b2[(0 * 8 + k) * 16 + tid];
        s_b2i[tid] = b2[(1 * 8 + k) * 16 + tid];
    }
    float2* q2 = f2 + (size_t)((bb * 8 + k) * 65 + wg * 2) * 2048;
    for (int it = 0; it < 16; ++it) {
        int u = tid + it * 256;
        int wl = u >> 11, rem = u & 2047;
        int h = rem >> 4, c = rem & 15;
        float2 v = (wl < ncol) ? q2[(size_t)wl * 2048 + rem] : make_float2(0.f, 0.f);
        re[h * LPAD + 2 * c + wl] = v.x;
        im[h * LPAD + 2 * c + wl] = v.y;
    }
    __syncthreads();
    // forward DIF along h (natural in -> bitrev out)
    for (int s = 7; s >= 1; --s) {
        int half = 1 << (s - 1);
        for (int it = 0; it < 8; ++it) {
            int u = tid + it * 256;
            int cw = u & 31, t = u >> 5;
            int j = t & (half - 1), g = t >> (s - 1);
            int i0 = (g << s) + j, i1 = i0 + half;
            float wr = twr[j << (7 - s)], wi = twi[j << (7 - s)];
            int a0 = i0 * LPAD + cw, a1 = i1 * LPAD + cw;
            float ar = re[a0], ai = im[a0];
            float br = re[a1], bi = im[a1];
            float dr = ar - br, di = ai - bi;
            re[a0] = ar + br; im[a0] = ai + bi;
            re[a1] = dr * wr - di * wi;
            im[a1] = dr * wi + di * wr;
        }
        __syncthreads();
    }
    // gating: one (spectral slot, w) per thread; slots are thread-private in LDS
    {
        int pos = tid >> 1, wl = tid & 1;
        int lb = pos * LPAD + wl;
        float vr[16], vi[16], o1r[16], o1i[16];
        #pragma unroll
        for (int c = 0; c < 16; ++c) { vr[c] = re[lb + 2 * c]; vi[c] = im[lb + 2 * c]; }
        #pragma unroll
        for (int o = 0; o < 16; ++o) { o1r[o] = s_b1r[o]; o1i[o] = s_b1i[o]; }
        #pragma unroll
        for (int c = 0; c < 16; ++c) {
            #pragma unroll
            for (int o = 0; o < 16; ++o) {
                float wr = s_w1r[c * 16 + o], wi = s_w1i[c * 16 + o];
                o1r[o] += vr[c] * wr - vi[c] * wi;
                o1i[o] += vi[c] * wr + vr[c] * wi;
            }
        }
        #pragma unroll
        for (int o = 0; o < 16; ++o) {
            float ar = s_b2r[o], ai = s_b2i[o];
            #pragma unroll
            for (int c = 0; c < 16; ++c) {
                float wr = s_w2r[c * 16 + o], wi = s_w2i[c * 16 + o];
                ar += o1r[c] * wr - o1i[c] * wi;
                ai += o1i[c] * wr + o1r[c] * wi;
            }
            ar = copysignf(fmaxf(fabsf(ar) - LAMBD, 0.0f), ar);
            ai = copysignf(fmaxf(fabsf(ai) - LAMBD, 0.0f), ai);
            re[lb + 2 * o] = ar * vr[o] - ai * vi[o];
            im[lb + 2 * o] = ar * vi[o] + ai * vr[o];
        }
    }
    __syncthreads();
    // inverse DIT along h (bitrev in -> natural out), conj twiddles
    for (int s = 1; s <= 7; ++s) {
        int half = 1 << (s - 1);
        for (int it = 0; it < 8; ++it) {
            int u = tid + it * 256;
            int cw = u & 31, t = u >> 5;
            int j = t & (half - 1), g = t >> (s - 1);
            int i0 = (g << s) + j, i1 = i0 + half;
            float wr = twr[j << (7 - s)], wi = twi[j << (7 - s)];
            int a0 = i0 * LPAD + cw, a1 = i1 * LPAD + cw;
            float ar = re[a0], ai = im[a0];
            float br = re[a1], bi = im[a1];
            float tr = br * wr + bi * wi;   // b * conj(tw)
            float ti = bi * wr - br * wi;
            re[a0] = ar + tr; im[a0] = ai + ti;
            re[a1] = ar - tr; im[a1] = ai - ti;
        }
        __syncthreads();
    }
    const float scale = 1.0f / 128.0f;  // column-inverse scale
    for (int it = 0; it < 16; ++it) {
        int u = tid + it * 256;
        int wl = u >> 11, rem = u & 2047;
        int h = rem >> 4, c = rem & 15;
        if (wl < ncol) {
            int l = h * LPAD + 2 * c + wl;
            q2[(size_t)wl * 2048 + rem] = make_float2(re[l] * scale, im[l] * scale);
        }
    }
}

// ---------------- Pass 2: row irFFT from f2 + residual add into y ----------------
__global__ __launch_bounds__(256) void rowifft_kernel(const float2* __restrict__ f2,
                                                      float* __restrict__ y) {
    __shared__ float re[32 * 129], im[32 * 129];
    __shared__ float twr[64], twi[64];
    int tid = threadIdx.x;
    int ht = blockIdx.x, k = blockIdx.y, bb = blockIdx.z;
    if (tid < 64) {
        float sv, cv;
        sincosf(-6.283185307179586f * (float)tid / 128.0f, &sv, &cv);
        twr[tid] = cv; twi[tid] = sv;
    }
    const float2* src = f2 + (size_t)((bb * 8 + k) * 65) * 2048 + ht * 32;
    for (int it = 0; it < 9; ++it) {
        int u = tid + it * 256;
        if (u < 2080) {
            int w = u >> 5, r = u & 31;
            float2 v = src[(size_t)w * 2048 + r];
            re[r * 129 + w] = v.x; im[r * 129 + w] = v.y;
            if (w > 0 && w < 64) {          // Hermitian mirror
                re[r * 129 + 128 - w] = v.x;
                im[r * 129 + 128 - w] = -v.y;
            }
        }
    }
    __syncthreads();
    // inverse DIF (natural in -> bitrev out), conj twiddles
    for (int s = 7; s >= 1; --s) {
        int half = 1 << (s - 1);
        for (int it = 0; it < 8; ++it) {
            int u = tid + it * 256;
            int row = u >> 6, t = u & 63;
            int j = t & (half - 1), g = t >> (s - 1);
            int i0 = (g << s) + j, i1 = i0 + half;
            float wr = twr[j << (7 - s)], wi = twi[j << (7 - s)];
            int a0 = row * 129 + i0, a1 = row * 129 + i1;
            float ar = re[a0], ai = im[a0];
            float br = re[a1], bi = im[a1];
            float dr = ar - br, di = ai - bi;
            re[a0] = ar + br; im[a0] = ai + bi;
            re[a1] = dr * wr + di * wi;     // (a-b) * conj(tw)
            im[a1] = di * wr - dr * wi;
        }
        __syncthreads();
    }
    // time sample t sits at bitrev slot; add residual, in place on y
    for (int it = 0; it < 16; ++it) {
        int u = tid + it * 256;
        int r = u >> 7, t = u & 127;
        int c16 = r & 15, hh = r >> 4;
        int h = ht * 2 + hh;
        size_t off = ((size_t)(bb * 128 + k * 16 + c16) * 128 + h) * 128 + t;
        y[off] += re[r * 129 + brev7(t)];
    }
}

// ---------------- Pass 3: bilinear 2x upsample + bias x, 4 outputs / thread ----------------
__global__ __launch_bounds__(256) void upsample_kernel(const float* __restrict__ s, const float* __restrict__ x,
                                                       float* __restrict__ out) {
    int t4 = blockIdx.x * blockDim.x + threadIdx.x;
    int tJ = t4 & 63;
    int r  = t4 >> 6;
    int I  = r & 255;
    int bc = r >> 8;
    float syf = (float)I * 0.5f - 0.25f;
    int y0 = (int)floorf(syf);
    float fy = syf - (float)y0;
    int y1 = y0 + 1; if (y1 > 127) y1 = 127; if (y0 < 0) y0 = 0;
    int u = 2 * tJ;
    int cm1 = u - 1; if (cm1 < 0) cm1 = 0;
    int cp1 = u + 1; if (cp1 > 127) cp1 = 127;
    int cp2 = u + 2; if (cp2 > 127) cp2 = 127;
    const float* sp = s + (size_t)bc * (128 * 128);
    const float* r0p = sp + y0 * 128;
    const float* r1p = sp + y1 * 128;
    float am1 = r0p[cm1], a0 = r0p[u], ap1 = r0p[cp1], ap2 = r0p[cp2];
    float bm1 = r1p[cm1], b0 = r1p[u], bp1 = r1p[cp1], bp2 = r1p[cp2];
    float rm1 = am1 + fy * (bm1 - am1);
    float rr0 = a0  + fy * (b0  - a0);
    float rp1 = ap1 + fy * (bp1 - ap1);
    float rp2 = ap2 + fy * (bp2 - ap2);
    float4 xv = *(const float4*)(x + (size_t)t4 * 4);
    float4 o;
    o.x = rm1 + 0.75f * (rr0 - rm1) + xv.x;
    o.y = rr0 + 0.25f * (rp1 - rr0) + xv.y;
    o.z = rr0 + 0.75f * (rp1 - rr0) + xv.z;
    o.w = rp1 + 0.25f * (rp2 - rp1) + xv.w;
    *(float4*)(out + (size_t)t4 * 4) = o;
}

extern "C" void kernel_launch(void* const* d_in, const int* in_sizes, int n_in,
                              void* d_out, int out_size, void* d_ws, size_t ws_size,
                              hipStream_t stream) {
    const float* x  = (const float*)d_in[0];
    const float* w1 = (const float*)d_in[1];
    const float* b1 = (const float*)d_in[2];
    const float* w2 = (const float*)d_in[3];
    const float* b2 = (const float*)d_in[4];
    float*  out = (float*)d_out;
    float*  y   = (float*)d_ws;      // 64 MB: pooled image, then s = irfft + y
    float2* f2  = (float2*)d_out;    // 68 MB transposed spectral scratch inside d_out

    poolfft_kernel<<<dim3(64, 8, 8), 256, 0, stream>>>(x, y, f2);
    specfused_kernel<<<dim3(33, 8, 8), 256, 0, stream>>>(f2, w1, b1, w2, b2);
    rowifft_kernel<<<dim3(64, 8, 8), 256, 0, stream>>>(f2, y);
    upsample_kernel<<<1024 * 256 * 64 / 256, 256, 0, stream>>>(y, x, out);
}

// Round 4
// 319.491 us; speedup vs baseline: 1.6595x; 1.2425x over previous
//
#include <hip/hip_runtime.h>
#include <math.h>

typedef __attribute__((ext_vector_type(2))) float f2;

#define LPITCH 33        // f2 pitch per position row (128 rows x 33 lanes)
#define LAMBD 0.01f

__device__ __forceinline__ int brev7(int n) { return (int)(__brev((unsigned)n) >> 25); }

__device__ __forceinline__ f2 cmulF(f2 a, f2 w) {   // a * w
    return (f2){ a.x*w.x - a.y*w.y, a.x*w.y + a.y*w.x };
}
__device__ __forceinline__ f2 cmulC(f2 a, f2 w) {   // a * conj(w)
    return (f2){ a.x*w.x + a.y*w.y, a.y*w.x - a.x*w.y };
}

__device__ __forceinline__ void tw_init(f2* TW, int tid) {
    if (tid < 64) {
        float sv, cv;
        sincosf(-6.283185307179586f * (float)tid / 128.0f, &sv, &cv);
        TW[tid] = (f2){cv, sv};   // W^j = e^{-2pi i j/128}
    }
}

template <bool CONJ>
__device__ __forceinline__ f2 twmul(f2 a, f2 w) { return CONJ ? cmulC(a, w) : cmulF(a, w); }

// ================= DIF passes: natural in -> bitrev out (CONJ=true: inverse, unscaled) ==========
template <bool CONJ>
__device__ __forceinline__ void dif_passA(f2* S, const f2* TW, int tid) {  // stages 7,6
    int cw = tid & 31, t = tid >> 5;
    #pragma unroll
    for (int gi = 0; gi < 4; ++gi) {
        int p = t * 4 + gi;                 // 0..31, constant per 32-lane group
        f2* s0 = S + (size_t)p * LPITCH + cw;
        f2 a = s0[0], b = s0[32*LPITCH], c = s0[64*LPITCH], d = s0[96*LPITCH];
        f2 t0 = a - c, t1 = b - d;
        a = a + c; b = b + d;
        c = twmul<CONJ>(t0, TW[p]);
        d = twmul<CONJ>(t1, TW[p + 32]);
        f2 w6 = TW[2 * p];
        f2 u0 = a - b, u1 = c - d;
        a = a + b; c = c + d;
        b = twmul<CONJ>(u0, w6);
        d = twmul<CONJ>(u1, w6);
        s0[0] = a; s0[32*LPITCH] = b; s0[64*LPITCH] = c; s0[96*LPITCH] = d;
    }
}

template <bool CONJ>
__device__ __forceinline__ void dif_passB(f2* S, const f2* TW, int tid) {  // stages 5,4
    int cw = tid & 31, t = tid >> 5;
    #pragma unroll
    for (int gi = 0; gi < 4; ++gi) {
        int idx = t * 4 + gi;
        int g = idx >> 3, j = idx & 7;
        f2* s0 = S + (size_t)(g * 32 + j) * LPITCH + cw;
        f2 a = s0[0], b = s0[8*LPITCH], c = s0[16*LPITCH], d = s0[24*LPITCH];
        f2 t0 = a - c, t1 = b - d;
        a = a + c; b = b + d;
        c = twmul<CONJ>(t0, TW[j << 2]);
        d = twmul<CONJ>(t1, TW[(j + 8) << 2]);
        f2 w4 = TW[j << 3];
        f2 u0 = a - b, u1 = c - d;
        a = a + b; c = c + d;
        b = twmul<CONJ>(u0, w4);
        d = twmul<CONJ>(u1, w4);
        s0[0] = a; s0[8*LPITCH] = b; s0[16*LPITCH] = c; s0[24*LPITCH] = d;
    }
}

template <bool CONJ>
__device__ __forceinline__ void dif_passC(f2* S, const f2* TW, int tid) {  // stages 3,2,1
    int cw = tid & 31, t = tid >> 5;
    #pragma unroll
    for (int gi = 0; gi < 2; ++gi) {
        int g = t * 2 + gi;                 // 0..15
        f2* s0 = S + (size_t)(g * 8) * LPITCH + cw;
        f2 v[8];
        #pragma unroll
        for (int o = 0; o < 8; ++o) v[o] = s0[o*LPITCH];
        #pragma unroll
        for (int o = 0; o < 4; ++o) {       // stage 3 (dist 4)
            f2 d = v[o] - v[o+4];
            v[o] = v[o] + v[o+4];
            v[o+4] = twmul<CONJ>(d, TW[o << 4]);
        }
        #pragma unroll
        for (int h2 = 0; h2 < 8; h2 += 4) { // stage 2 (dist 2)
            #pragma unroll
            for (int o = 0; o < 2; ++o) {
                int i0 = h2 + o;
                f2 d = v[i0] - v[i0+2];
                v[i0] = v[i0] + v[i0+2];
                v[i0+2] = twmul<CONJ>(d, TW[o << 5]);
            }
        }
        #pragma unroll
        for (int e = 0; e < 8; e += 2) {    // stage 1 (dist 1), tw^0
            f2 d = v[e] - v[e+1];
            v[e] = v[e] + v[e+1];
            v[e+1] = d;
        }
        #pragma unroll
        for (int o = 0; o < 8; ++o) s0[o*LPITCH] = v[o];
    }
}

// ================= DIT inverse passes: bitrev in -> natural out (conj twiddles) =================
__device__ __forceinline__ void dit_passC(f2* S, const f2* TW, int tid) {  // stages 1,2,3
    int cw = tid & 31, t = tid >> 5;
    #pragma unroll
    for (int gi = 0; gi < 2; ++gi) {
        int g = t * 2 + gi;
        f2* s0 = S + (size_t)(g * 8) * LPITCH + cw;
        f2 v[8];
        #pragma unroll
        for (int o = 0; o < 8; ++o) v[o] = s0[o*LPITCH];
        #pragma unroll
        for (int e = 0; e < 8; e += 2) {    // stage 1
            f2 tt = v[e+1];
            v[e+1] = v[e] - tt;
            v[e]   = v[e] + tt;
        }
        #pragma unroll
        for (int h2 = 0; h2 < 8; h2 += 4) { // stage 2
            #pragma unroll
            for (int o = 0; o < 2; ++o) {
                int i0 = h2 + o;
                f2 tt = cmulC(v[i0+2], TW[o << 5]);
                v[i0+2] = v[i0] - tt;
                v[i0]   = v[i0] + tt;
            }
        }
        #pragma unroll
        for (int o = 0; o < 4; ++o) {       // stage 3
            f2 tt = cmulC(v[o+4], TW[o << 4]);
            v[o+4] = v[o] - tt;
            v[o]   = v[o] + tt;
        }
        #pragma unroll
        for (int o = 0; o < 8; ++o) s0[o*LPITCH] = v[o];
    }
}

__device__ __forceinline__ void dit_passB(f2* S, const f2* TW, int tid) {  // stages 4,5
    int cw = tid & 31, t = tid >> 5;
    #pragma unroll
    for (int gi = 0; gi < 4; ++gi) {
        int idx = t * 4 + gi;
        int g = idx >> 3, j = idx & 7;
        f2* s0 = S + (size_t)(g * 32 + j) * LPITCH + cw;
        f2 a = s0[0], b = s0[8*LPITCH], c = s0[16*LPITCH], d = s0[24*LPITCH];
        f2 w4 = TW[j << 3];
        f2 tb = cmulC(b, w4), td = cmulC(d, w4);
        b = a - tb; a = a + tb;
        d = c - td; c = c + td;
        f2 tc = cmulC(c, TW[j << 2]);
        f2 te = cmulC(d, TW[(j + 8) << 2]);
        c = a - tc; a = a + tc;
        d = b - te; b = b + te;
        s0[0] = a; s0[8*LPITCH] = b; s0[16*LPITCH] = c; s0[24*LPITCH] = d;
    }
}

__device__ __forceinline__ void dit_passA(f2* S, const f2* TW, int tid) {  // stages 6,7
    int cw = tid & 31, t = tid >> 5;
    #pragma unroll
    for (int gi = 0; gi < 4; ++gi) {
        int p = t * 4 + gi;
        f2* s0 = S + (size_t)p * LPITCH + cw;
        f2 a = s0[0], b = s0[32*LPITCH], c = s0[64*LPITCH], d = s0[96*LPITCH];
        f2 w6 = TW[2 * p];
        f2 tb = cmulC(b, w6), td = cmulC(d, w6);
        b = a - tb; a = a + tb;
        d = c - td; c = c + td;
        f2 tc = cmulC(c, TW[p]);
        f2 te = cmulC(d, TW[p + 32]);
        c = a - tc; a = a + tc;
        d = b - te; b = b + te;
        s0[0] = a; s0[32*LPITCH] = b; s0[64*LPITCH] = c; s0[96*LPITCH] = d;
    }
}

// ================= Pass 0: pool + row rFFT (along w) -> transposed fg =================
__global__ __launch_bounds__(256) void poolfft_kernel(const float* __restrict__ x,
                                                      float* __restrict__ y,
                                                      f2* __restrict__ fg) {
    __shared__ f2 S[128 * LPITCH];
    __shared__ f2 TW[64];
    int tid = threadIdx.x;
    int ht = blockIdx.x, k = blockIdx.y, bb = blockIdx.z;
    tw_init(TW, tid);
    #pragma unroll
    for (int it = 0; it < 8; ++it) {
        int u = tid + it * 256;
        int r = u >> 6, q = u & 63;          // r = hh*16 + c16 (lane), q = w quad
        int c16 = r & 15, hh = r >> 4;
        int h = ht * 2 + hh;
        const float* p = x + (((size_t)(bb*128 + k*16 + c16) * 256 + 2*h) * 256 + 4*q);
        float4 a = *(const float4*)p;
        float4 b = *(const float4*)(p + 256);
        float v0 = fmaxf(fmaxf(a.x,a.y), fmaxf(b.x,b.y)) + 0.25f*(a.x+a.y+b.x+b.y);
        float v1 = fmaxf(fmaxf(a.z,a.w), fmaxf(b.z,b.w)) + 0.25f*(a.z+a.w+b.z+b.w);
        *(f2*)(y + ((size_t)(bb*128 + k*16 + c16)*128 + h)*128 + 2*q) = (f2){v0, v1};
        S[(2*q)*LPITCH + r]   = (f2){v0, 0.f};
        S[(2*q+1)*LPITCH + r] = (f2){v1, 0.f};
    }
    __syncthreads();
    dif_passA<false>(S, TW, tid); __syncthreads();
    dif_passB<false>(S, TW, tid); __syncthreads();
    dif_passC<false>(S, TW, tid); __syncthreads();
    const float scale = 1.0f / 128.0f;       // full forward ortho scale
    f2* dst = fg + (size_t)((bb*8 + k) * 65) * 2048 + ht * 32;
    #pragma unroll
    for (int it = 0; it < 9; ++it) {
        int u = tid + it * 256;
        if (u < 2080) {
            int w = u >> 5, r = u & 31;
            f2 v = S[brev7(w)*LPITCH + r];   // bin w sits at bitrev slot
            dst[(size_t)w * 2048 + r] = v * scale;
        }
    }
}

// ================= Pass 1: col FFT fwd + gating MLP (scalar weights) + col FFT inv ==============
__global__ __launch_bounds__(256) void specfused_kernel(f2* __restrict__ fg,
        const float* __restrict__ w1, const float* __restrict__ b1,
        const float* __restrict__ w2, const float* __restrict__ b2) {
    __shared__ f2 S[128 * LPITCH];
    __shared__ f2 TW[64];
    int tid = threadIdx.x;
    int wg = blockIdx.x, k = blockIdx.y, bb = blockIdx.z;
    int ncol = (wg == 32) ? 1 : 2;
    tw_init(TW, tid);
    f2* q2 = fg + (size_t)((bb*8 + k) * 65 + wg * 2) * 2048;
    #pragma unroll
    for (int it = 0; it < 16; ++it) {
        int u = tid + it * 256;
        int wl = u >> 11, rem = u & 2047;
        int h = rem >> 4, c = rem & 15;
        f2 v = (wl < ncol) ? q2[(size_t)wl * 2048 + rem] : (f2){0.f, 0.f};
        S[h*LPITCH + 2*c + wl] = v;
    }
    __syncthreads();
    dif_passA<false>(S, TW, tid); __syncthreads();
    dif_passB<false>(S, TW, tid); __syncthreads();
    dif_passC<false>(S, TW, tid); __syncthreads();
    // gating: thread-private (h-slot, w) position; weights via block-uniform scalar loads
    {
        const float* w1r = w1 + k*256;       const float* w1i = w1 + 2048 + k*256;
        const float* w2r = w2 + k*256;       const float* w2i = w2 + 2048 + k*256;
        const float* b1r = b1 + k*16;        const float* b1i = b1 + 128 + k*16;
        const float* b2r = b2 + k*16;        const float* b2i = b2 + 128 + k*16;
        int pos = tid >> 1, wl = tid & 1;
        f2* sp = S + pos * LPITCH + wl;
        f2 v[16], o1[16], g[16];
        #pragma unroll
        for (int c = 0; c < 16; ++c) v[c] = sp[2*c];
        #pragma unroll
        for (int o = 0; o < 16; ++o) o1[o] = (f2){b1r[o], b1i[o]};
        #pragma unroll
        for (int c = 0; c < 16; ++c) {
            f2 vc = v[c];
            f2 vs = (f2){-vc.y, vc.x};
            #pragma unroll
            for (int o = 0; o < 16; ++o)
                o1[o] += vc * w1r[c*16+o] + vs * w1i[c*16+o];   // 2x v_pk_fma_f32
        }
        #pragma unroll
        for (int o = 0; o < 16; ++o) g[o] = (f2){b2r[o], b2i[o]};
        #pragma unroll
        for (int c = 0; c < 16; ++c) {
            f2 vc = o1[c];
            f2 vs = (f2){-vc.y, vc.x};
            #pragma unroll
            for (int o = 0; o < 16; ++o)
                g[o] += vc * w2r[c*16+o] + vs * w2i[c*16+o];
        }
        #pragma unroll
        for (int o = 0; o < 16; ++o) {
            f2 gg = g[o];
            float ar = copysignf(fmaxf(fabsf(gg.x) - LAMBD, 0.f), gg.x);
            float ai = copysignf(fmaxf(fabsf(gg.y) - LAMBD, 0.f), gg.y);
            sp[2*o] = cmulF(v[o], (f2){ar, ai});   // z = g * f
        }
    }
    __syncthreads();
    dit_passC(S, TW, tid); __syncthreads();
    dit_passB(S, TW, tid); __syncthreads();
    dit_passA(S, TW, tid); __syncthreads();
    const float scale = 1.0f / 128.0f;       // full inverse scale carried here
    #pragma unroll
    for (int it = 0; it < 16; ++it) {
        int u = tid + it * 256;
        int wl = u >> 11, rem = u & 2047;
        int h = rem >> 4, c = rem & 15;
        if (wl < ncol)
            q2[(size_t)wl * 2048 + rem] = S[h*LPITCH + 2*c + wl] * scale;
    }
}

// ================= Pass 2: row irFFT (along w) + residual add into y =================
__global__ __launch_bounds__(256) void rowifft_kernel(const f2* __restrict__ fg,
                                                      float* __restrict__ y) {
    __shared__ f2 S[128 * LPITCH];
    __shared__ f2 TW[64];
    int tid = threadIdx.x;
    int ht = blockIdx.x, k = blockIdx.y, bb = blockIdx.z;
    tw_init(TW, tid);
    const f2* src = fg + (size_t)((bb*8 + k) * 65) * 2048 + ht * 32;
    #pragma unroll
    for (int it = 0; it < 9; ++it) {
        int u = tid + it * 256;
        if (u < 2080) {
            int w = u >> 5, r = u & 31;
            f2 v = src[(size_t)w * 2048 + r];
            S[w*LPITCH + r] = v;
            if (w > 0 && w < 64) S[(128 - w)*LPITCH + r] = (f2){v.x, -v.y};  // Hermitian
        }
    }
    __syncthreads();
    dif_passA<true>(S, TW, tid); __syncthreads();
    dif_passB<true>(S, TW, tid); __syncthreads();
    dif_passC<true>(S, TW, tid); __syncthreads();
    // spatial sample t at bitrev slot; add residual in place on y
    #pragma unroll
    for (int it = 0; it < 16; ++it) {
        int u = tid + it * 256;
        int t = u & 127, r = u >> 7;
        int c16 = r & 15, hh = r >> 4;
        int h = ht * 2 + hh;
        size_t off = ((size_t)(bb*128 + k*16 + c16) * 128 + h) * 128 + t;
        y[off] += S[brev7(t)*LPITCH + r].x;
    }
}

// ================= Pass 3: bilinear 2x upsample + bias x, 4 outputs / thread =================
__global__ __launch_bounds__(256) void upsample_kernel(const float* __restrict__ s, const float* __restrict__ x,
                                                       float* __restrict__ out) {
    int t4 = blockIdx.x * blockDim.x + threadIdx.x;
    int tJ = t4 & 63;
    int r  = t4 >> 6;
    int I  = r & 255;
    int bc = r >> 8;
    float syf = (float)I * 0.5f - 0.25f;
    int y0 = (int)floorf(syf);
    float fy = syf - (float)y0;
    int y1 = y0 + 1; if (y1 > 127) y1 = 127; if (y0 < 0) y0 = 0;
    int u = 2 * tJ;
    int cm1 = u - 1; if (cm1 < 0) cm1 = 0;
    int cp1 = u + 1; if (cp1 > 127) cp1 = 127;
    int cp2 = u + 2; if (cp2 > 127) cp2 = 127;
    const float* sp = s + (size_t)bc * (128 * 128);
    const float* r0p = sp + y0 * 128;
    const float* r1p = sp + y1 * 128;
    float am1 = r0p[cm1], a0 = r0p[u], ap1 = r0p[cp1], ap2 = r0p[cp2];
    float bm1 = r1p[cm1], b0 = r1p[u], bp1 = r1p[cp1], bp2 = r1p[cp2];
    float rm1 = am1 + fy * (bm1 - am1);
    float rr0 = a0  + fy * (b0  - a0);
    float rp1 = ap1 + fy * (bp1 - ap1);
    float rp2 = ap2 + fy * (bp2 - ap2);
    float4 xv = *(const float4*)(x + (size_t)t4 * 4);
    float4 o;
    o.x = rm1 + 0.75f * (rr0 - rm1) + xv.x;
    o.y = rr0 + 0.25f * (rp1 - rr0) + xv.y;
    o.z = rr0 + 0.75f * (rp1 - rr0) + xv.z;
    o.w = rp1 + 0.25f * (rp2 - rp1) + xv.w;
    *(float4*)(out + (size_t)t4 * 4) = o;
}

extern "C" void kernel_launch(void* const* d_in, const int* in_sizes, int n_in,
                              void* d_out, int out_size, void* d_ws, size_t ws_size,
                              hipStream_t stream) {
    const float* x  = (const float*)d_in[0];
    const float* w1 = (const float*)d_in[1];
    const float* b1 = (const float*)d_in[2];
    const float* w2 = (const float*)d_in[3];
    const float* b2 = (const float*)d_in[4];
    float* out = (float*)d_out;
    float* y   = (float*)d_ws;     // 64 MB: pooled image, then s = irfft + y
    f2*    fg  = (f2*)d_out;       // 68 MB transposed spectral scratch inside d_out

    poolfft_kernel<<<dim3(64, 8, 8), 256, 0, stream>>>(x, y, fg);
    specfused_kernel<<<dim3(33, 8, 8), 256, 0, stream>>>(fg, w1, b1, w2, b2);
    rowifft_kernel<<<dim3(64, 8, 8), 256, 0, stream>>>(fg, y);
    upsample_kernel<<<1024 * 256 * 64 / 256, 256, 0, stream>>>(y, x, out);
}

// Round 5
// 280.231 us; speedup vs baseline: 1.8920x; 1.1401x over previous
//
#include <hip/hip_runtime.h>
#include <math.h>

typedef __attribute__((ext_vector_type(2))) float f2;
typedef __attribute__((ext_vector_type(2))) _Float16 h2;

#define LPITCH 33        // f2 pitch per position row (128 rows x 33 lanes)
#define LAMBD 0.01f

__device__ __forceinline__ int brev7(int n) { return (int)(__brev((unsigned)n) >> 25); }

__device__ __forceinline__ f2 cmulF(f2 a, f2 w) {   // a * w
    return (f2){ a.x*w.x - a.y*w.y, a.x*w.y + a.y*w.x };
}
__device__ __forceinline__ f2 cmulC(f2 a, f2 w) {   // a * conj(w)
    return (f2){ a.x*w.x + a.y*w.y, a.y*w.x - a.x*w.y };
}
__device__ __forceinline__ h2 tohalf(f2 v) { return (h2){(_Float16)v.x, (_Float16)v.y}; }
__device__ __forceinline__ f2 tofloat(h2 v) { return (f2){(float)v.x, (float)v.y}; }

#define RC 0.70710678118654752440f

__device__ __forceinline__ f2 mul_mi(f2 a)  { return (f2){ a.y, -a.x}; }                    // * -i
__device__ __forceinline__ f2 mul_pi(f2 a)  { return (f2){-a.y,  a.x}; }                    // * +i
__device__ __forceinline__ f2 mul_w81(f2 a) { return (f2){ RC*(a.x+a.y),  RC*(a.y-a.x)}; }  // * (RC - iRC)
__device__ __forceinline__ f2 mul_w83(f2 a) { return (f2){ RC*(a.y-a.x), -RC*(a.x+a.y)}; }  // * (-RC - iRC)
__device__ __forceinline__ f2 mul_w8m1(f2 a){ return (f2){ RC*(a.x-a.y),  RC*(a.x+a.y)}; }  // * (RC + iRC)
__device__ __forceinline__ f2 mul_w8m3(f2 a){ return (f2){-RC*(a.x+a.y),  RC*(a.x-a.y)}; }  // * (-RC + iRC)

// in-register 16-point FFT, DIF: natural in, out reg r holds bin brev4(r).
template <bool INV>
__device__ __forceinline__ void fft16(f2* v) {
    constexpr float C8 = 0.92387953251128675613f, S8 = 0.38268343236508977173f;
    constexpr float WR[8] = {1.f,  C8,  RC,  S8, 0.f, -S8, -RC, -C8};
    constexpr float WI[8] = {0.f, -S8, -RC, -C8, -1.f, -C8, -RC, -S8};
    #pragma unroll
    for (int j = 0; j < 8; ++j) {
        f2 d = v[j] - v[j+8]; v[j] += v[j+8];
        f2 w = (f2){WR[j], INV ? -WI[j] : WI[j]};
        v[j+8] = (j == 0) ? d : cmulF(d, w);
    }
    #pragma unroll
    for (int gg = 0; gg < 16; gg += 8) {
        #pragma unroll
        for (int j = 0; j < 4; ++j) {
            int i = gg + j;
            f2 d = v[i] - v[i+4]; v[i] += v[i+4];
            f2 w = (f2){WR[2*j], INV ? -WI[2*j] : WI[2*j]};
            v[i+4] = (j == 0) ? d : cmulF(d, w);
        }
    }
    #pragma unroll
    for (int gg = 0; gg < 16; gg += 4) {
        f2 d0 = v[gg] - v[gg+2];   v[gg]   += v[gg+2]; v[gg+2] = d0;
        f2 d1 = v[gg+1] - v[gg+3]; v[gg+1] += v[gg+3]; v[gg+3] = INV ? mul_pi(d1) : mul_mi(d1);
    }
    #pragma unroll
    for (int gg = 0; gg < 16; gg += 2) {
        f2 d = v[gg] - v[gg+1]; v[gg] += v[gg+1]; v[gg+1] = d;
    }
}

// in-register 8-point DFT, DIF: natural in, out reg r holds bin brev3(r).
template <bool INV>
__device__ __forceinline__ void dft8(f2* g) {
    f2 d0 = g[0]-g[4]; g[0]+=g[4]; g[4] = d0;
    f2 d1 = g[1]-g[5]; g[1]+=g[5]; g[5] = INV ? mul_w8m1(d1) : mul_w81(d1);
    f2 d2 = g[2]-g[6]; g[2]+=g[6]; g[6] = INV ? mul_pi(d2)   : mul_mi(d2);
    f2 d3 = g[3]-g[7]; g[3]+=g[7]; g[7] = INV ? mul_w8m3(d3) : mul_w83(d3);
    f2 e0 = g[0]-g[2]; g[0]+=g[2]; g[2] = e0;
    f2 e1 = g[1]-g[3]; g[1]+=g[3]; g[3] = INV ? mul_pi(e1) : mul_mi(e1);
    f2 e4 = g[4]-g[6]; g[4]+=g[6]; g[6] = e4;
    f2 e5 = g[5]-g[7]; g[5]+=g[7]; g[7] = INV ? mul_pi(e5) : mul_mi(e5);
    f2 f0 = g[0]-g[1]; g[0]+=g[1]; g[1] = f0;
    f2 f1 = g[2]-g[3]; g[2]+=g[3]; g[3] = f1;
    f2 f4 = g[4]-g[5]; g[4]+=g[5]; g[5] = f4;
    f2 f6 = g[6]-g[7]; g[6]+=g[7]; g[7] = f6;
}

__device__ __forceinline__ void tw_init(f2* TW, int tid) {
    if (tid < 64) {
        float sv, cv;
        sincosf(-6.283185307179586f * (float)tid / 128.0f, &sv, &cv);
        TW[tid] = (f2){cv, sv};
    }
}

// ============ 2-stage LDS FFT passes (poolfft / rowifft, proven in R4) ============
template <bool CONJ>
__device__ __forceinline__ f2 twmul(f2 a, f2 w) { return CONJ ? cmulC(a, w) : cmulF(a, w); }

template <bool CONJ>
__device__ __forceinline__ void dif_passA(f2* S, const f2* TW, int tid) {  // stages 7,6
    int cw = tid & 31, t = tid >> 5;
    #pragma unroll
    for (int gi = 0; gi < 4; ++gi) {
        int p = t * 4 + gi;
        f2* s0 = S + (size_t)p * LPITCH + cw;
        f2 a = s0[0], b = s0[32*LPITCH], c = s0[64*LPITCH], d = s0[96*LPITCH];
        f2 t0 = a - c, t1 = b - d;
        a = a + c; b = b + d;
        c = twmul<CONJ>(t0, TW[p]);
        d = twmul<CONJ>(t1, TW[p + 32]);
        f2 w6 = TW[2 * p];
        f2 u0 = a - b, u1 = c - d;
        a = a + b; c = c + d;
        b = twmul<CONJ>(u0, w6);
        d = twmul<CONJ>(u1, w6);
        s0[0] = a; s0[32*LPITCH] = b; s0[64*LPITCH] = c; s0[96*LPITCH] = d;
    }
}

template <bool CONJ>
__device__ __forceinline__ void dif_passB(f2* S, const f2* TW, int tid) {  // stages 5,4
    int cw = tid & 31, t = tid >> 5;
    #pragma unroll
    for (int gi = 0; gi < 4; ++gi) {
        int idx = t * 4 + gi;
        int g = idx >> 3, j = idx & 7;
        f2* s0 = S + (size_t)(g * 32 + j) * LPITCH + cw;
        f2 a = s0[0], b = s0[8*LPITCH], c = s0[16*LPITCH], d = s0[24*LPITCH];
        f2 t0 = a - c, t1 = b - d;
        a = a + c; b = b + d;
        c = twmul<CONJ>(t0, TW[j << 2]);
        d = twmul<CONJ>(t1, TW[(j + 8) << 2]);
        f2 w4 = TW[j << 3];
        f2 u0 = a - b, u1 = c - d;
        a = a + b; c = c + d;
        b = twmul<CONJ>(u0, w4);
        d = twmul<CONJ>(u1, w4);
        s0[0] = a; s0[8*LPITCH] = b; s0[16*LPITCH] = c; s0[24*LPITCH] = d;
    }
}

template <bool CONJ>
__device__ __forceinline__ void dif_passC(f2* S, const f2* TW, int tid) {  // stages 3,2,1
    int cw = tid & 31, t = tid >> 5;
    #pragma unroll
    for (int gi = 0; gi < 2; ++gi) {
        int g = t * 2 + gi;
        f2* s0 = S + (size_t)(g * 8) * LPITCH + cw;
        f2 v[8];
        #pragma unroll
        for (int o = 0; o < 8; ++o) v[o] = s0[o*LPITCH];
        #pragma unroll
        for (int o = 0; o < 4; ++o) {
            f2 d = v[o] - v[o+4];
            v[o] = v[o] + v[o+4];
            v[o+4] = twmul<CONJ>(d, TW[o << 4]);
        }
        #pragma unroll
        for (int h2i = 0; h2i < 8; h2i += 4) {
            #pragma unroll
            for (int o = 0; o < 2; ++o) {
                int i0 = h2i + o;
                f2 d = v[i0] - v[i0+2];
                v[i0] = v[i0] + v[i0+2];
                v[i0+2] = twmul<CONJ>(d, TW[o << 5]);
            }
        }
        #pragma unroll
        for (int e = 0; e < 8; e += 2) {
            f2 d = v[e] - v[e+1];
            v[e] = v[e] + v[e+1];
            v[e+1] = d;
        }
        #pragma unroll
        for (int o = 0; o < 8; ++o) s0[o*LPITCH] = v[o];
    }
}

// ================= Pass 0: pool + row rFFT (along w) -> transposed fg (fp16) =================
__global__ __launch_bounds__(256) void poolfft_kernel(const float* __restrict__ x,
                                                      _Float16* __restrict__ yh,
                                                      h2* __restrict__ fgh) {
    __shared__ f2 S[128 * LPITCH];
    __shared__ f2 TW[64];
    int tid = threadIdx.x;
    int ht = blockIdx.x, k = blockIdx.y, bb = blockIdx.z;
    tw_init(TW, tid);
    #pragma unroll
    for (int it = 0; it < 8; ++it) {
        int u = tid + it * 256;
        int r = u >> 6, q = u & 63;          // r = hh*16 + c16 (lane), q = w quad
        int c16 = r & 15, hh = r >> 4;
        int h = ht * 2 + hh;
        const float* p = x + (((size_t)(bb*128 + k*16 + c16) * 256 + 2*h) * 256 + 4*q);
        float4 a = *(const float4*)p;
        float4 b = *(const float4*)(p + 256);
        float v0 = fmaxf(fmaxf(a.x,a.y), fmaxf(b.x,b.y)) + 0.25f*(a.x+a.y+b.x+b.y);
        float v1 = fmaxf(fmaxf(a.z,a.w), fmaxf(b.z,b.w)) + 0.25f*(a.z+a.w+b.z+b.w);
        *(h2*)(yh + (((size_t)(bb*128 + k*16 + c16)*128 + h)*128 + 2*q)) = (h2){(_Float16)v0, (_Float16)v1};
        S[(2*q)*LPITCH + r]   = (f2){v0, 0.f};
        S[(2*q+1)*LPITCH + r] = (f2){v1, 0.f};
    }
    __syncthreads();
    dif_passA<false>(S, TW, tid); __syncthreads();
    dif_passB<false>(S, TW, tid); __syncthreads();
    dif_passC<false>(S, TW, tid); __syncthreads();
    const float scale = 1.0f / 128.0f;       // full forward ortho scale
    h2* dst = fgh + (size_t)((bb*8 + k) * 65) * 2048 + ht * 32;
    #pragma unroll
    for (int it = 0; it < 9; ++it) {
        int u = tid + it * 256;
        if (u < 2080) {
            int w = u >> 5, r = u & 31;
            f2 v = S[brev7(w)*LPITCH + r];   // bin w sits at bitrev slot
            dst[(size_t)w * 2048 + r] = tohalf(v * scale);
        }
    }
}

// ======== Pass 1: col FFT fwd (radix 16x8, in-register) + gating + col FFT inv ========
__global__ __launch_bounds__(256) void specfused_kernel(h2* __restrict__ fgh,
        const float* __restrict__ w1, const float* __restrict__ b1,
        const float* __restrict__ w2, const float* __restrict__ b2) {
    __shared__ f2 S[128 * LPITCH];
    __shared__ f2 TW[128];
    int tid = threadIdx.x;
    int wg = blockIdx.x, k = blockIdx.y, bb = blockIdx.z;
    int ncol = (wg == 32) ? 1 : 2;
    if (tid < 128) {
        float sv, cv;
        sincosf(-6.283185307179586f * (float)tid / 128.0f, &sv, &cv);
        TW[tid] = (f2){cv, sv};
    }
    constexpr int BR4[16] = {0,8,4,12,2,10,6,14,1,9,5,13,3,11,7,15};
    constexpr int BR3[8]  = {0,4,2,6,1,5,3,7};
    h2* q2 = fgh + (size_t)((bb*8 + k) * 65 + wg * 2) * 2048;
    #pragma unroll
    for (int it = 0; it < 16; ++it) {
        int u = tid + it * 256;
        int wl = u >> 11, rem = u & 2047;
        int h = rem >> 4, c = rem & 15;
        f2 v = (wl < ncol) ? tofloat(q2[(size_t)wl*2048 + rem]) : (f2){0.f, 0.f};
        S[h*LPITCH + 2*c + wl] = v;
    }
    __syncthreads();
    int cw = tid & 31, t = tid >> 5;   // t = 0..7 (= n2)
    f2* Scw = S + cw;
    // ---- forward: FFT16 over n1 (in-thread), twiddle, transpose, DFT8 over n2 ----
    {
        f2 v[16];
        #pragma unroll
        for (int j = 0; j < 16; ++j) v[j] = Scw[(8*j + t) * LPITCH];   // x[8*n1 + t], rows owned by (t,cw)
        fft16<false>(v);
        #pragma unroll
        for (int r = 0; r < 16; ++r) {
            int k1 = BR4[r];
            Scw[(k1*8 + t) * LPITCH] = cmulF(v[r], TW[t * k1]);        // same owned rows
        }
    }
    __syncthreads();
    {
        f2 a[8], b[8];
        int k1a = 2*t, k1b = 2*t + 1;
        #pragma unroll
        for (int n2 = 0; n2 < 8; ++n2) {
            a[n2] = Scw[(k1a*8 + n2) * LPITCH];
            b[n2] = Scw[(k1b*8 + n2) * LPITCH];
        }
        dft8<false>(a); dft8<false>(b);
        __syncthreads();
        #pragma unroll
        for (int r = 0; r < 8; ++r) {
            int k2 = BR3[r];
            Scw[(k1a + 16*k2) * LPITCH] = a[r];    // natural bin order
            Scw[(k1b + 16*k2) * LPITCH] = b[r];
        }
    }
    __syncthreads();
    // ---- gating: thread-private (bin, w) position; weights via block-uniform scalar loads ----
    {
        const float* w1r = w1 + k*256;       const float* w1i = w1 + 2048 + k*256;
        const float* w2r = w2 + k*256;       const float* w2i = w2 + 2048 + k*256;
        const float* b1r = b1 + k*16;        const float* b1i = b1 + 128 + k*16;
        const float* b2r = b2 + k*16;        const float* b2i = b2 + 128 + k*16;
        int pos = tid >> 1, wl = tid & 1;
        f2* sp = S + pos * LPITCH + wl;
        f2 v[16], o1[16], g[16];
        #pragma unroll
        for (int c = 0; c < 16; ++c) v[c] = sp[2*c];
        #pragma unroll
        for (int o = 0; o < 16; ++o) o1[o] = (f2){b1r[o], b1i[o]};
        #pragma unroll
        for (int c = 0; c < 16; ++c) {
            f2 vc = v[c];
            f2 vs = (f2){-vc.y, vc.x};
            #pragma unroll
            for (int o = 0; o < 16; ++o)
                o1[o] += vc * w1r[c*16+o] + vs * w1i[c*16+o];
        }
        #pragma unroll
        for (int o = 0; o < 16; ++o) g[o] = (f2){b2r[o], b2i[o]};
        #pragma unroll
        for (int c = 0; c < 16; ++c) {
            f2 vc = o1[c];
            f2 vs = (f2){-vc.y, vc.x};
            #pragma unroll
            for (int o = 0; o < 16; ++o)
                g[o] += vc * w2r[c*16+o] + vs * w2i[c*16+o];
        }
        #pragma unroll
        for (int o = 0; o < 16; ++o) {
            f2 gg = g[o];
            float ar = copysignf(fmaxf(fabsf(gg.x) - LAMBD, 0.f), gg.x);
            float ai = copysignf(fmaxf(fabsf(gg.y) - LAMBD, 0.f), gg.y);
            sp[2*o] = cmulF(v[o], (f2){ar, ai});   // z = g * f
        }
    }
    __syncthreads();
    // ---- inverse: IDFT8 over k2, conj twiddle, transpose, IFFT16 over k1 ----
    {
        f2 a[8], b[8];
        int k1a = 2*t, k1b = 2*t + 1;
        #pragma unroll
        for (int k2 = 0; k2 < 8; ++k2) {
            a[k2] = Scw[(k1a + 16*k2) * LPITCH];
            b[k2] = Scw[(k1b + 16*k2) * LPITCH];
        }
        dft8<true>(a); dft8<true>(b);
        __syncthreads();
        #pragma unroll
        for (int r = 0; r < 8; ++r) {
            int n2 = BR3[r];
            Scw[(k1a*8 + n2) * LPITCH] = cmulC(a[r], TW[n2 * k1a]);
            Scw[(k1b*8 + n2) * LPITCH] = cmulC(b[r], TW[n2 * k1b]);
        }
    }
    __syncthreads();
    {
        f2 v[16];
        #pragma unroll
        for (int j = 0; j < 16; ++j) v[j] = Scw[(8*j + t) * LPITCH];   // G'(k1=j, n2=t)
        fft16<true>(v);
        #pragma unroll
        for (int r = 0; r < 16; ++r)
            Scw[(8*BR4[r] + t) * LPITCH] = v[r];                       // spatial n = 8*n1 + t
    }
    __syncthreads();
    const float scale = 1.0f / 128.0f;   // full inverse scale carried here
    #pragma unroll
    for (int it = 0; it < 16; ++it) {
        int u = tid + it * 256;
        int wl = u >> 11, rem = u & 2047;
        int h = rem >> 4, c = rem & 15;
        if (wl < ncol)
            q2[(size_t)wl*2048 + rem] = tohalf(S[h*LPITCH + 2*c + wl] * scale);
    }
}

// ================= Pass 2: row irFFT (along w) + residual add into y (fp16) =================
__global__ __launch_bounds__(256) void rowifft_kernel(const h2* __restrict__ fgh,
                                                      _Float16* __restrict__ yh) {
    __shared__ f2 S[128 * LPITCH];
    __shared__ f2 TW[64];
    int tid = threadIdx.x;
    int ht = blockIdx.x, k = blockIdx.y, bb = blockIdx.z;
    tw_init(TW, tid);
    const h2* src = fgh + (size_t)((bb*8 + k) * 65) * 2048 + ht * 32;
    #pragma unroll
    for (int it = 0; it < 9; ++it) {
        int u = tid + it * 256;
        if (u < 2080) {
            int w = u >> 5, r = u & 31;
            f2 v = tofloat(src[(size_t)w * 2048 + r]);
            S[w*LPITCH + r] = v;
            if (w > 0 && w < 64) S[(128 - w)*LPITCH + r] = (f2){v.x, -v.y};  // Hermitian
        }
    }
    __syncthreads();
    dif_passA<true>(S, TW, tid); __syncthreads();
    dif_passB<true>(S, TW, tid); __syncthreads();
    dif_passC<true>(S, TW, tid); __syncthreads();
    // spatial sample t at bitrev slot; s = irfft + y, in place on yh (fp16 pairs)
    #pragma unroll
    for (int it = 0; it < 8; ++it) {
        int u = tid + it * 256;
        int r = u >> 6, tp = u & 63;
        int c16 = r & 15, hh = r >> 4;
        int h = ht * 2 + hh;
        size_t offp = ((size_t)(bb*128 + k*16 + c16) * 128 + h) * 64 + tp;
        h2* yp = (h2*)yh + offp;
        h2 old = *yp;
        int p0 = brev7(2*tp);
        float s0 = (float)old.x + S[p0*LPITCH + r].x;
        float s1 = (float)old.y + S[(p0+64)*LPITCH + r].x;
        *yp = (h2){(_Float16)s0, (_Float16)s1};
    }
}

// ================= Pass 3: bilinear 2x upsample + bias x, 4 outputs / thread =================
__global__ __launch_bounds__(256) void upsample_kernel(const _Float16* __restrict__ sh,
                                                       const float* __restrict__ x,
                                                       float* __restrict__ out) {
    int t4 = blockIdx.x * blockDim.x + threadIdx.x;
    int tJ = t4 & 63;
    int r  = t4 >> 6;
    int I  = r & 255;
    int bc = r >> 8;
    float syf = (float)I * 0.5f - 0.25f;
    int y0 = (int)floorf(syf);
    float fy = syf - (float)y0;
    int y1 = y0 + 1; if (y1 > 127) y1 = 127; if (y0 < 0) y0 = 0;
    const h2* r0 = (const h2*)(sh + ((size_t)bc * 128 + y0) * 128);
    const h2* r1 = (const h2*)(sh + ((size_t)bc * 128 + y1) * 128);
    int pm = (tJ == 0)  ? 0  : tJ - 1;
    int pp = (tJ == 63) ? 63 : tJ + 1;
    h2 a_m = r0[pm], a_0 = r0[tJ], a_p = r0[pp];
    h2 b_m = r1[pm], b_0 = r1[tJ], b_p = r1[pp];
    float am1 = (tJ == 0)  ? (float)a_0.x : (float)a_m.y;
    float a0  = (float)a_0.x, ap1 = (float)a_0.y;
    float ap2 = (tJ == 63) ? (float)a_p.y : (float)a_p.x;
    float bm1 = (tJ == 0)  ? (float)b_0.x : (float)b_m.y;
    float b0  = (float)b_0.x, bp1 = (float)b_0.y;
    float bp2 = (tJ == 63) ? (float)b_p.y : (float)b_p.x;
    float rm1 = am1 + fy * (bm1 - am1);
    float rr0 = a0  + fy * (b0  - a0);
    float rp1 = ap1 + fy * (bp1 - ap1);
    float rp2 = ap2 + fy * (bp2 - ap2);
    float4 xv = *(const float4*)(x + (size_t)t4 * 4);
    float4 o;
    o.x = rm1 + 0.75f * (rr0 - rm1) + xv.x;
    o.y = rr0 + 0.25f * (rp1 - rr0) + xv.y;
    o.z = rr0 + 0.75f * (rp1 - rr0) + xv.z;
    o.w = rp1 + 0.25f * (rp2 - rp1) + xv.w;
    *(float4*)(out + (size_t)t4 * 4) = o;
}

extern "C" void kernel_launch(void* const* d_in, const int* in_sizes, int n_in,
                              void* d_out, int out_size, void* d_ws, size_t ws_size,
                              hipStream_t stream) {
    const float* x  = (const float*)d_in[0];
    const float* w1 = (const float*)d_in[1];
    const float* b1 = (const float*)d_in[2];
    const float* w2 = (const float*)d_in[3];
    const float* b2 = (const float*)d_in[4];
    float*     out = (float*)d_out;
    _Float16*  yh  = (_Float16*)d_ws;  // 33.5 MB: pooled image, then s = irfft + y (fp16)
    h2*        fgh = (h2*)d_out;       // 34 MB transposed spectral scratch inside d_out (fp16 pairs)

    poolfft_kernel<<<dim3(64, 8, 8), 256, 0, stream>>>(x, yh, fgh);
    specfused_kernel<<<dim3(33, 8, 8), 256, 0, stream>>>(fgh, w1, b1, w2, b2);
    rowifft_kernel<<<dim3(64, 8, 8), 256, 0, stream>>>(fgh, yh);
    upsample_kernel<<<1024 * 256 * 64 / 256, 256, 0, stream>>>(yh, x, out);
}

// Round 6
// 275.109 us; speedup vs baseline: 1.9272x; 1.0186x over previous
//
#include <hip/hip_runtime.h>
#include <math.h>

typedef __attribute__((ext_vector_type(2))) float f2;
typedef __attribute__((ext_vector_type(2))) _Float16 h2;

#define LPITCH 33        // f2 pitch per position row (128 rows x 33 lanes)
#define LAMBD 0.01f

__device__ __forceinline__ f2 cmulF(f2 a, f2 w) {   // a * w
    return (f2){ a.x*w.x - a.y*w.y, a.x*w.y + a.y*w.x };
}
__device__ __forceinline__ f2 cmulC(f2 a, f2 w) {   // a * conj(w)
    return (f2){ a.x*w.x + a.y*w.y, a.y*w.x - a.x*w.y };
}
__device__ __forceinline__ h2 tohalf(f2 v) { return (h2){(_Float16)v.x, (_Float16)v.y}; }
__device__ __forceinline__ f2 tofloat(h2 v) { return (f2){(float)v.x, (float)v.y}; }

#define RC 0.70710678118654752440f

__device__ __forceinline__ f2 mul_mi(f2 a)  { return (f2){ a.y, -a.x}; }                    // * -i
__device__ __forceinline__ f2 mul_pi(f2 a)  { return (f2){-a.y,  a.x}; }                    // * +i
__device__ __forceinline__ f2 mul_w81(f2 a) { return (f2){ RC*(a.x+a.y),  RC*(a.y-a.x)}; }  // * (RC - iRC)
__device__ __forceinline__ f2 mul_w83(f2 a) { return (f2){ RC*(a.y-a.x), -RC*(a.x+a.y)}; }  // * (-RC - iRC)
__device__ __forceinline__ f2 mul_w8m1(f2 a){ return (f2){ RC*(a.x-a.y),  RC*(a.x+a.y)}; }  // * (RC + iRC)
__device__ __forceinline__ f2 mul_w8m3(f2 a){ return (f2){-RC*(a.x+a.y),  RC*(a.x-a.y)}; }  // * (-RC + iRC)

// in-register 16-point FFT, DIF: natural in, out reg r holds bin brev4(r).
template <bool INV>
__device__ __forceinline__ void fft16(f2* v) {
    constexpr float C8 = 0.92387953251128675613f, S8 = 0.38268343236508977173f;
    constexpr float WR[8] = {1.f,  C8,  RC,  S8, 0.f, -S8, -RC, -C8};
    constexpr float WI[8] = {0.f, -S8, -RC, -C8, -1.f, -C8, -RC, -S8};
    #pragma unroll
    for (int j = 0; j < 8; ++j) {
        f2 d = v[j] - v[j+8]; v[j] += v[j+8];
        f2 w = (f2){WR[j], INV ? -WI[j] : WI[j]};
        v[j+8] = (j == 0) ? d : cmulF(d, w);
    }
    #pragma unroll
    for (int gg = 0; gg < 16; gg += 8) {
        #pragma unroll
        for (int j = 0; j < 4; ++j) {
            int i = gg + j;
            f2 d = v[i] - v[i+4]; v[i] += v[i+4];
            f2 w = (f2){WR[2*j], INV ? -WI[2*j] : WI[2*j]};
            v[i+4] = (j == 0) ? d : cmulF(d, w);
        }
    }
    #pragma unroll
    for (int gg = 0; gg < 16; gg += 4) {
        f2 d0 = v[gg] - v[gg+2];   v[gg]   += v[gg+2]; v[gg+2] = d0;
        f2 d1 = v[gg+1] - v[gg+3]; v[gg+1] += v[gg+3]; v[gg+3] = INV ? mul_pi(d1) : mul_mi(d1);
    }
    #pragma unroll
    for (int gg = 0; gg < 16; gg += 2) {
        f2 d = v[gg] - v[gg+1]; v[gg] += v[gg+1]; v[gg+1] = d;
    }
}

// in-register 8-point DFT, DIF: natural in, out reg r holds bin brev3(r).
template <bool INV>
__device__ __forceinline__ void dft8(f2* g) {
    f2 d0 = g[0]-g[4]; g[0]+=g[4]; g[4] = d0;
    f2 d1 = g[1]-g[5]; g[1]+=g[5]; g[5] = INV ? mul_w8m1(d1) : mul_w81(d1);
    f2 d2 = g[2]-g[6]; g[2]+=g[6]; g[6] = INV ? mul_pi(d2)   : mul_mi(d2);
    f2 d3 = g[3]-g[7]; g[3]+=g[7]; g[7] = INV ? mul_w8m3(d3) : mul_w83(d3);
    f2 e0 = g[0]-g[2]; g[0]+=g[2]; g[2] = e0;
    f2 e1 = g[1]-g[3]; g[1]+=g[3]; g[3] = INV ? mul_pi(e1) : mul_mi(e1);
    f2 e4 = g[4]-g[6]; g[4]+=g[6]; g[6] = e4;
    f2 e5 = g[5]-g[7]; g[5]+=g[7]; g[7] = INV ? mul_pi(e5) : mul_mi(e5);
    f2 f0 = g[0]-g[1]; g[0]+=g[1]; g[1] = f0;
    f2 f1 = g[2]-g[3]; g[2]+=g[3]; g[3] = f1;
    f2 f4 = g[4]-g[5]; g[4]+=g[5]; g[5] = f4;
    f2 f6 = g[6]-g[7]; g[6]+=g[7]; g[7] = f6;
}

__device__ __forceinline__ void tw128_init(f2* TW, int tid) {
    if (tid < 128) {
        float sv, cv;
        sincosf(-6.283185307179586f * (float)tid / 128.0f, &sv, &cv);
        TW[tid] = (f2){cv, sv};
    }
}

// ================= Pass 0: pool + row rFFT (radix 16x8) -> transposed fg (fp16) =================
__global__ __launch_bounds__(256) void poolfft_kernel(const float* __restrict__ x,
                                                      _Float16* __restrict__ yh,
                                                      h2* __restrict__ fgh) {
    __shared__ f2 S[128 * LPITCH];
    __shared__ f2 TW[128];
    int tid = threadIdx.x;
    int ht = blockIdx.x, k = blockIdx.y, bb = blockIdx.z;
    tw128_init(TW, tid);
    constexpr int BR4[16] = {0,8,4,12,2,10,6,14,1,9,5,13,3,11,7,15};
    constexpr int BR3[8]  = {0,4,2,6,1,5,3,7};
    #pragma unroll
    for (int it = 0; it < 8; ++it) {
        int u = tid + it * 256;
        int r = u >> 6, q = u & 63;          // r = hh*16 + c16 (lane), q = w quad
        int c16 = r & 15, hh = r >> 4;
        int h = ht * 2 + hh;
        const float* p = x + (((size_t)(bb*128 + k*16 + c16) * 256 + 2*h) * 256 + 4*q);
        float4 a = *(const float4*)p;
        float4 b = *(const float4*)(p + 256);
        float v0 = fmaxf(fmaxf(a.x,a.y), fmaxf(b.x,b.y)) + 0.25f*(a.x+a.y+b.x+b.y);
        float v1 = fmaxf(fmaxf(a.z,a.w), fmaxf(b.z,b.w)) + 0.25f*(a.z+a.w+b.z+b.w);
        *(h2*)(yh + (((size_t)(bb*128 + k*16 + c16)*128 + h)*128 + 2*q)) = (h2){(_Float16)v0, (_Float16)v1};
        S[(2*q)*LPITCH + r]   = (f2){v0, 0.f};
        S[(2*q+1)*LPITCH + r] = (f2){v1, 0.f};
    }
    __syncthreads();
    int cw = tid & 31, t = tid >> 5;         // t = n2 (0..7)
    f2* Scw = S + cw;
    {   // FFT16 over n1 (in registers)
        f2 v[16];
        #pragma unroll
        for (int j = 0; j < 16; ++j) v[j] = Scw[(8*j + t) * LPITCH];
        fft16<false>(v);
        #pragma unroll
        for (int r = 0; r < 16; ++r) {
            int k1 = BR4[r];
            Scw[(k1*8 + t) * LPITCH] = cmulF(v[r], TW[t * k1]);
        }
    }
    __syncthreads();
    {   // DFT8 over n2, natural bin output
        f2 a[8], b[8];
        int k1a = 2*t, k1b = 2*t + 1;
        #pragma unroll
        for (int n2 = 0; n2 < 8; ++n2) {
            a[n2] = Scw[(k1a*8 + n2) * LPITCH];
            b[n2] = Scw[(k1b*8 + n2) * LPITCH];
        }
        dft8<false>(a); dft8<false>(b);
        __syncthreads();
        #pragma unroll
        for (int r = 0; r < 8; ++r) {
            int k2 = BR3[r];
            Scw[(k1a + 16*k2) * LPITCH] = a[r];
            Scw[(k1b + 16*k2) * LPITCH] = b[r];
        }
    }
    __syncthreads();
    const float scale = 1.0f / 128.0f;       // full forward ortho scale
    h2* dst = fgh + (size_t)((bb*8 + k) * 65) * 2048 + ht * 32;
    #pragma unroll
    for (int it = 0; it < 9; ++it) {
        int u = tid + it * 256;
        if (u < 2080) {
            int w = u >> 5, r = u & 31;
            dst[(size_t)w * 2048 + r] = tohalf(S[w*LPITCH + r] * scale);
        }
    }
}

// ======== Pass 1: col FFT fwd (radix 16x8, in-register) + gating + col FFT inv ========
__global__ __launch_bounds__(256) void specfused_kernel(h2* __restrict__ fgh,
        const float* __restrict__ w1, const float* __restrict__ b1,
        const float* __restrict__ w2, const float* __restrict__ b2) {
    __shared__ f2 S[128 * LPITCH];
    __shared__ f2 TW[128];
    int tid = threadIdx.x;
    int wg = blockIdx.x, k = blockIdx.y, bb = blockIdx.z;
    int ncol = (wg == 32) ? 1 : 2;
    tw128_init(TW, tid);
    constexpr int BR4[16] = {0,8,4,12,2,10,6,14,1,9,5,13,3,11,7,15};
    constexpr int BR3[8]  = {0,4,2,6,1,5,3,7};
    h2* q2 = fgh + (size_t)((bb*8 + k) * 65 + wg * 2) * 2048;
    #pragma unroll
    for (int it = 0; it < 16; ++it) {
        int u = tid + it * 256;
        int wl = u >> 11, rem = u & 2047;
        int h = rem >> 4, c = rem & 15;
        f2 v = (wl < ncol) ? tofloat(q2[(size_t)wl*2048 + rem]) : (f2){0.f, 0.f};
        S[h*LPITCH + 2*c + wl] = v;
    }
    __syncthreads();
    int cw = tid & 31, t = tid >> 5;   // t = 0..7 (= n2)
    f2* Scw = S + cw;
    {   // forward: FFT16 over n1, twiddle, transpose
        f2 v[16];
        #pragma unroll
        for (int j = 0; j < 16; ++j) v[j] = Scw[(8*j + t) * LPITCH];
        fft16<false>(v);
        #pragma unroll
        for (int r = 0; r < 16; ++r) {
            int k1 = BR4[r];
            Scw[(k1*8 + t) * LPITCH] = cmulF(v[r], TW[t * k1]);
        }
    }
    __syncthreads();
    {
        f2 a[8], b[8];
        int k1a = 2*t, k1b = 2*t + 1;
        #pragma unroll
        for (int n2 = 0; n2 < 8; ++n2) {
            a[n2] = Scw[(k1a*8 + n2) * LPITCH];
            b[n2] = Scw[(k1b*8 + n2) * LPITCH];
        }
        dft8<false>(a); dft8<false>(b);
        __syncthreads();
        #pragma unroll
        for (int r = 0; r < 8; ++r) {
            int k2 = BR3[r];
            Scw[(k1a + 16*k2) * LPITCH] = a[r];    // natural bin order
            Scw[(k1b + 16*k2) * LPITCH] = b[r];
        }
    }
    __syncthreads();
    // ---- gating: thread-private (bin, w) position; weights via block-uniform scalar loads ----
    {
        const float* w1r = w1 + k*256;       const float* w1i = w1 + 2048 + k*256;
        const float* w2r = w2 + k*256;       const float* w2i = w2 + 2048 + k*256;
        const float* b1r = b1 + k*16;        const float* b1i = b1 + 128 + k*16;
        const float* b2r = b2 + k*16;        const float* b2i = b2 + 128 + k*16;
        int pos = tid >> 1, wl = tid & 1;
        f2* sp = S + pos * LPITCH + wl;
        f2 v[16], o1[16], g[16];
        #pragma unroll
        for (int c = 0; c < 16; ++c) v[c] = sp[2*c];
        #pragma unroll
        for (int o = 0; o < 16; ++o) o1[o] = (f2){b1r[o], b1i[o]};
        #pragma unroll
        for (int c = 0; c < 16; ++c) {
            f2 vc = v[c];
            f2 vs = (f2){-vc.y, vc.x};
            #pragma unroll
            for (int o = 0; o < 16; ++o)
                o1[o] += vc * w1r[c*16+o] + vs * w1i[c*16+o];
        }
        #pragma unroll
        for (int o = 0; o < 16; ++o) g[o] = (f2){b2r[o], b2i[o]};
        #pragma unroll
        for (int c = 0; c < 16; ++c) {
            f2 vc = o1[c];
            f2 vs = (f2){-vc.y, vc.x};
            #pragma unroll
            for (int o = 0; o < 16; ++o)
                g[o] += vc * w2r[c*16+o] + vs * w2i[c*16+o];
        }
        #pragma unroll
        for (int o = 0; o < 16; ++o) {
            f2 gg = g[o];
            float ar = copysignf(fmaxf(fabsf(gg.x) - LAMBD, 0.f), gg.x);
            float ai = copysignf(fmaxf(fabsf(gg.y) - LAMBD, 0.f), gg.y);
            sp[2*o] = cmulF(v[o], (f2){ar, ai});   // z = g * f
        }
    }
    __syncthreads();
    {   // inverse: IDFT8 over k2, conj twiddle, transpose
        f2 a[8], b[8];
        int k1a = 2*t, k1b = 2*t + 1;
        #pragma unroll
        for (int k2 = 0; k2 < 8; ++k2) {
            a[k2] = Scw[(k1a + 16*k2) * LPITCH];
            b[k2] = Scw[(k1b + 16*k2) * LPITCH];
        }
        dft8<true>(a); dft8<true>(b);
        __syncthreads();
        #pragma unroll
        for (int r = 0; r < 8; ++r) {
            int n2 = BR3[r];
            Scw[(k1a*8 + n2) * LPITCH] = cmulC(a[r], TW[n2 * k1a]);
            Scw[(k1b*8 + n2) * LPITCH] = cmulC(b[r], TW[n2 * k1b]);
        }
    }
    __syncthreads();
    {   // IFFT16 over k1 (thread-private slots)
        f2 v[16];
        #pragma unroll
        for (int j = 0; j < 16; ++j) v[j] = Scw[(8*j + t) * LPITCH];
        fft16<true>(v);
        #pragma unroll
        for (int r = 0; r < 16; ++r)
            Scw[(8*BR4[r] + t) * LPITCH] = v[r];                       // spatial n = 8*n1 + t
    }
    __syncthreads();
    const float scale = 1.0f / 128.0f;   // full inverse scale carried here
    #pragma unroll
    for (int it = 0; it < 16; ++it) {
        int u = tid + it * 256;
        int wl = u >> 11, rem = u & 2047;
        int h = rem >> 4, c = rem & 15;
        if (wl < ncol)
            q2[(size_t)wl*2048 + rem] = tohalf(S[h*LPITCH + 2*c + wl] * scale);
    }
}

// ============ Pass 2: row irFFT (radix 16x8) + residual add into y (fp16) ============
__global__ __launch_bounds__(256) void rowifft_kernel(const h2* __restrict__ fgh,
                                                      _Float16* __restrict__ yh) {
    __shared__ f2 S[128 * LPITCH];
    __shared__ f2 TW[128];
    int tid = threadIdx.x;
    int ht = blockIdx.x, k = blockIdx.y, bb = blockIdx.z;
    tw128_init(TW, tid);
    constexpr int BR4[16] = {0,8,4,12,2,10,6,14,1,9,5,13,3,11,7,15};
    constexpr int BR3[8]  = {0,4,2,6,1,5,3,7};
    const h2* src = fgh + (size_t)((bb*8 + k) * 65) * 2048 + ht * 32;
    #pragma unroll
    for (int it = 0; it < 9; ++it) {
        int u = tid + it * 256;
        if (u < 2080) {
            int w = u >> 5, r = u & 31;
            f2 v = tofloat(src[(size_t)w * 2048 + r]);
            S[w*LPITCH + r] = v;
            if (w > 0 && w < 64) S[(128 - w)*LPITCH + r] = (f2){v.x, -v.y};  // Hermitian
        }
    }
    __syncthreads();
    int cw = tid & 31, t = tid >> 5;
    f2* Scw = S + cw;
    {   // IDFT8 over k2, conj twiddle, transpose
        f2 a[8], b[8];
        int k1a = 2*t, k1b = 2*t + 1;
        #pragma unroll
        for (int k2 = 0; k2 < 8; ++k2) {
            a[k2] = Scw[(k1a + 16*k2) * LPITCH];
            b[k2] = Scw[(k1b + 16*k2) * LPITCH];
        }
        dft8<true>(a); dft8<true>(b);
        __syncthreads();
        #pragma unroll
        for (int r = 0; r < 8; ++r) {
            int n2 = BR3[r];
            Scw[(k1a*8 + n2) * LPITCH] = cmulC(a[r], TW[n2 * k1a]);
            Scw[(k1b*8 + n2) * LPITCH] = cmulC(b[r], TW[n2 * k1b]);
        }
    }
    __syncthreads();
    {   // IFFT16 over k1 (thread-private slots), natural spatial output
        f2 v[16];
        #pragma unroll
        for (int j = 0; j < 16; ++j) v[j] = Scw[(8*j + t) * LPITCH];
        fft16<true>(v);
        #pragma unroll
        for (int r = 0; r < 16; ++r)
            Scw[(8*BR4[r] + t) * LPITCH] = v[r];
    }
    __syncthreads();
    // s = irfft + y, in place on yh (fp16 pairs); natural spatial order in S
    #pragma unroll
    for (int it = 0; it < 8; ++it) {
        int u = tid + it * 256;
        int r = u >> 6, tp = u & 63;
        int c16 = r & 15, hh = r >> 4;
        int h = ht * 2 + hh;
        size_t offp = ((size_t)(bb*128 + k*16 + c16) * 128 + h) * 64 + tp;
        h2* yp = (h2*)yh + offp;
        h2 old = *yp;
        float s0 = (float)old.x + S[(2*tp)*LPITCH + r].x;
        float s1 = (float)old.y + S[(2*tp+1)*LPITCH + r].x;
        *yp = (h2){(_Float16)s0, (_Float16)s1};
    }
}

// ================= Pass 3: bilinear 2x upsample + bias x, 8 outputs / thread =================
__global__ __launch_bounds__(256) void upsample_kernel(const _Float16* __restrict__ sh,
                                                       const float* __restrict__ x,
                                                       float* __restrict__ out) {
    int t8 = blockIdx.x * blockDim.x + threadIdx.x;  // one thread = 8 consecutive output cols
    int tJ = t8 & 31;          // output col group: J = 8*tJ
    int r  = t8 >> 5;
    int I  = r & 255;
    int bc = r >> 8;
    float syf = (float)I * 0.5f - 0.25f;
    int y0 = (int)floorf(syf);
    float fy = syf - (float)y0;
    int y1 = y0 + 1; if (y1 > 127) y1 = 127; if (y0 < 0) y0 = 0;
    const h2* r0 = (const h2*)(sh + ((size_t)bc * 128 + y0) * 128);
    const h2* r1 = (const h2*)(sh + ((size_t)bc * 128 + y1) * 128);
    int i0 = 2 * tJ;
    h2 A0 = r0[i0], A1 = r0[i0 + 1];
    h2 B0 = r1[i0], B1 = r1[i0 + 1];
    float am1 = (tJ == 0)  ? (float)A0.x : (float)r0[i0 - 1].y;
    float ap4 = (tJ == 31) ? (float)A1.y : (float)r0[i0 + 2].x;
    float bm1 = (tJ == 0)  ? (float)B0.x : (float)r1[i0 - 1].y;
    float bp4 = (tJ == 31) ? (float)B1.y : (float)r1[i0 + 2].x;
    // row-lerped source cols 4tJ-1 .. 4tJ+4
    float vm = am1 + fy * (bm1 - am1);
    float v0 = (float)A0.x + fy * ((float)B0.x - (float)A0.x);
    float v1 = (float)A0.y + fy * ((float)B0.y - (float)A0.y);
    float v2 = (float)A1.x + fy * ((float)B1.x - (float)A1.x);
    float v3 = (float)A1.y + fy * ((float)B1.y - (float)A1.y);
    float v4 = ap4 + fy * (bp4 - ap4);
    const float* xp = x + (size_t)t8 * 8;
    float4 x0 = *(const float4*)xp;
    float4 x1 = *(const float4*)(xp + 4);
    float4 o0, o1;
    o0.x = vm + 0.75f * (v0 - vm) + x0.x;
    o0.y = v0 + 0.25f * (v1 - v0) + x0.y;
    o0.z = v0 + 0.75f * (v1 - v0) + x0.z;
    o0.w = v1 + 0.25f * (v2 - v1) + x0.w;
    o1.x = v1 + 0.75f * (v2 - v1) + x1.x;
    o1.y = v2 + 0.25f * (v3 - v2) + x1.y;
    o1.z = v2 + 0.75f * (v3 - v2) + x1.z;
    o1.w = v3 + 0.25f * (v4 - v3) + x1.w;
    float* op = out + (size_t)t8 * 8;
    *(float4*)op = o0;
    *(float4*)(op + 4) = o1;
}

extern "C" void kernel_launch(void* const* d_in, const int* in_sizes, int n_in,
                              void* d_out, int out_size, void* d_ws, size_t ws_size,
                              hipStream_t stream) {
    const float* x  = (const float*)d_in[0];
    const float* w1 = (const float*)d_in[1];
    const float* b1 = (const float*)d_in[2];
    const float* w2 = (const float*)d_in[3];
    const float* b2 = (const float*)d_in[4];
    float*     out = (float*)d_out;
    _Float16*  yh  = (_Float16*)d_ws;  // 33.5 MB: pooled image, then s = irfft + y (fp16)
    h2*        fgh = (h2*)d_out;       // 34 MB transposed spectral scratch inside d_out (fp16 pairs)

    poolfft_kernel<<<dim3(64, 8, 8), 256, 0, stream>>>(x, yh, fgh);
    specfused_kernel<<<dim3(33, 8, 8), 256, 0, stream>>>(fgh, w1, b1, w2, b2);
    rowifft_kernel<<<dim3(64, 8, 8), 256, 0, stream>>>(fgh, yh);
    upsample_kernel<<<1024 * 256 * 32 / 256, 256, 0, stream>>>(yh, x, out);
}

// Round 10
// 274.858 us; speedup vs baseline: 1.9290x; 1.0009x over previous
//
#include <hip/hip_runtime.h>
#include <math.h>

typedef __attribute__((ext_vector_type(2))) float f2;
typedef __attribute__((ext_vector_type(2))) _Float16 h2;

#define LPITCH 33        // f2 pitch per position row (128 rows x 33 lanes)
#define LAMBD 0.01f

__device__ __forceinline__ f2 cmulF(f2 a, f2 w) {   // a * w
    return (f2){ a.x*w.x - a.y*w.y, a.x*w.y + a.y*w.x };
}
__device__ __forceinline__ f2 cmulC(f2 a, f2 w) {   // a * conj(w)
    return (f2){ a.x*w.x + a.y*w.y, a.y*w.x - a.x*w.y };
}
__device__ __forceinline__ h2 tohalf(f2 v) { return (h2){(_Float16)v.x, (_Float16)v.y}; }
__device__ __forceinline__ f2 tofloat(h2 v) { return (f2){(float)v.x, (float)v.y}; }

#define RC 0.70710678118654752440f

__device__ __forceinline__ f2 mul_mi(f2 a)  { return (f2){ a.y, -a.x}; }
__device__ __forceinline__ f2 mul_pi(f2 a)  { return (f2){-a.y,  a.x}; }
__device__ __forceinline__ f2 mul_w81(f2 a) { return (f2){ RC*(a.x+a.y),  RC*(a.y-a.x)}; }
__device__ __forceinline__ f2 mul_w83(f2 a) { return (f2){ RC*(a.y-a.x), -RC*(a.x+a.y)}; }
__device__ __forceinline__ f2 mul_w8m1(f2 a){ return (f2){ RC*(a.x-a.y),  RC*(a.x+a.y)}; }
__device__ __forceinline__ f2 mul_w8m3(f2 a){ return (f2){-RC*(a.x+a.y),  RC*(a.x-a.y)}; }

// in-register 16-point FFT, DIF: natural in, out reg r holds bin brev4(r).
template <bool INV>
__device__ __forceinline__ void fft16(f2* v) {
    constexpr float C8 = 0.92387953251128675613f, S8 = 0.38268343236508977173f;
    constexpr float WR[8] = {1.f,  C8,  RC,  S8, 0.f, -S8, -RC, -C8};
    constexpr float WI[8] = {0.f, -S8, -RC, -C8, -1.f, -C8, -RC, -S8};
    #pragma unroll
    for (int j = 0; j < 8; ++j) {
        f2 d = v[j] - v[j+8]; v[j] += v[j+8];
        f2 w = (f2){WR[j], INV ? -WI[j] : WI[j]};
        v[j+8] = (j == 0) ? d : cmulF(d, w);
    }
    #pragma unroll
    for (int gg = 0; gg < 16; gg += 8) {
        #pragma unroll
        for (int j = 0; j < 4; ++j) {
            int i = gg + j;
            f2 d = v[i] - v[i+4]; v[i] += v[i+4];
            f2 w = (f2){WR[2*j], INV ? -WI[2*j] : WI[2*j]};
            v[i+4] = (j == 0) ? d : cmulF(d, w);
        }
    }
    #pragma unroll
    for (int gg = 0; gg < 16; gg += 4) {
        f2 d0 = v[gg] - v[gg+2];   v[gg]   += v[gg+2]; v[gg+2] = d0;
        f2 d1 = v[gg+1] - v[gg+3]; v[gg+1] += v[gg+3]; v[gg+3] = INV ? mul_pi(d1) : mul_mi(d1);
    }
    #pragma unroll
    for (int gg = 0; gg < 16; gg += 2) {
        f2 d = v[gg] - v[gg+1]; v[gg] += v[gg+1]; v[gg+1] = d;
    }
}

// in-register 8-point DFT, DIF: natural in, out reg r holds bin brev3(r).
template <bool INV>
__device__ __forceinline__ void dft8(f2* g) {
    f2 d0 = g[0]-g[4]; g[0]+=g[4]; g[4] = d0;
    f2 d1 = g[1]-g[5]; g[1]+=g[5]; g[5] = INV ? mul_w8m1(d1) : mul_w81(d1);
    f2 d2 = g[2]-g[6]; g[2]+=g[6]; g[6] = INV ? mul_pi(d2)   : mul_mi(d2);
    f2 d3 = g[3]-g[7]; g[3]+=g[7]; g[7] = INV ? mul_w8m3(d3) : mul_w83(d3);
    f2 e0 = g[0]-g[2]; g[0]+=g[2]; g[2] = e0;
    f2 e1 = g[1]-g[3]; g[1]+=g[3]; g[3] = INV ? mul_pi(e1) : mul_mi(e1);
    f2 e4 = g[4]-g[6]; g[4]+=g[6]; g[6] = e4;
    f2 e5 = g[5]-g[7]; g[5]+=g[7]; g[7] = INV ? mul_pi(e5) : mul_mi(e5);
    f2 f0 = g[0]-g[1]; g[0]+=g[1]; g[1] = f0;
    f2 f1 = g[2]-g[3]; g[2]+=g[3]; g[3] = f1;
    f2 f4 = g[4]-g[5]; g[4]+=g[5]; g[5] = f4;
    f2 f6 = g[6]-g[7]; g[6]+=g[7]; g[7] = f6;
}

__device__ __forceinline__ void tw128_init(f2* TW, int tid) {
    if (tid < 128) {
        float sv, cv;
        sincosf(-6.283185307179586f * (float)tid / 128.0f, &sv, &cv);
        TW[tid] = (f2){cv, sv};
    }
}

// ================= Pass 0: pool + row rFFT (radix 16x8) -> transposed fg (fp16) =================
__global__ __launch_bounds__(256) void poolfft_kernel(const float* __restrict__ x,
                                                      _Float16* __restrict__ yh,
                                                      h2* __restrict__ fgh) {
    __shared__ f2 S[128 * LPITCH];
    __shared__ f2 TW[128];
    int tid = threadIdx.x;
    int ht = blockIdx.x, k = blockIdx.y, bb = blockIdx.z;
    tw128_init(TW, tid);
    constexpr int BR4[16] = {0,8,4,12,2,10,6,14,1,9,5,13,3,11,7,15};
    constexpr int BR3[8]  = {0,4,2,6,1,5,3,7};
    #pragma unroll
    for (int it = 0; it < 8; ++it) {
        int u = tid + it * 256;
        int r = u >> 6, q = u & 63;          // r = hh*16 + c16 (lane), q = w quad
        int c16 = r & 15, hh = r >> 4;
        int h = ht * 2 + hh;
        const float* p = x + (((size_t)(bb*128 + k*16 + c16) * 256 + 2*h) * 256 + 4*q);
        float4 a = *(const float4*)p;
        float4 b = *(const float4*)(p + 256);
        float v0 = fmaxf(fmaxf(a.x,a.y), fmaxf(b.x,b.y)) + 0.25f*(a.x+a.y+b.x+b.y);
        float v1 = fmaxf(fmaxf(a.z,a.w), fmaxf(b.z,b.w)) + 0.25f*(a.z+a.w+b.z+b.w);
        *(h2*)(yh + (((size_t)(bb*128 + k*16 + c16)*128 + h)*128 + 2*q)) = (h2){(_Float16)v0, (_Float16)v1};
        S[(2*q)*LPITCH + r]   = (f2){v0, 0.f};
        S[(2*q+1)*LPITCH + r] = (f2){v1, 0.f};
    }
    __syncthreads();
    int cw = tid & 31, t = tid >> 5;         // t = n2 (0..7)
    f2* Scw = S + cw;
    {   // FFT16 over n1 (in registers)
        f2 v[16];
        #pragma unroll
        for (int j = 0; j < 16; ++j) v[j] = Scw[(8*j + t) * LPITCH];
        fft16<false>(v);
        #pragma unroll
        for (int r = 0; r < 16; ++r) {
            int k1 = BR4[r];
            Scw[(k1*8 + t) * LPITCH] = cmulF(v[r], TW[t * k1]);
        }
    }
    __syncthreads();
    {   // DFT8 over n2, natural bin output
        f2 a[8], b[8];
        int k1a = 2*t, k1b = 2*t + 1;
        #pragma unroll
        for (int n2 = 0; n2 < 8; ++n2) {
            a[n2] = Scw[(k1a*8 + n2) * LPITCH];
            b[n2] = Scw[(k1b*8 + n2) * LPITCH];
        }
        dft8<false>(a); dft8<false>(b);
        __syncthreads();
        #pragma unroll
        for (int r = 0; r < 8; ++r) {
            int k2 = BR3[r];
            Scw[(k1a + 16*k2) * LPITCH] = a[r];
            Scw[(k1b + 16*k2) * LPITCH] = b[r];
        }
    }
    __syncthreads();
    const float scale = 1.0f / 128.0f;       // full forward ortho scale
    h2* dst = fgh + (size_t)((bb*8 + k) * 65) * 2048 + ht * 32;
    #pragma unroll
    for (int it = 0; it < 9; ++it) {
        int u = tid + it * 256;
        if (u < 2080) {
            int w = u >> 5, r = u & 31;
            dst[(size_t)w * 2048 + r] = tohalf(S[w*LPITCH + r] * scale);
        }
    }
}

// ======== Pass 1: col FFT fwd (radix 16x8, in-register) + gating + col FFT inv ========
__global__ __launch_bounds__(256) void specfused_kernel(h2* __restrict__ fgh,
        const float* __restrict__ w1, const float* __restrict__ b1,
        const float* __restrict__ w2, const float* __restrict__ b2) {
    __shared__ f2 S[128 * LPITCH];
    __shared__ f2 TW[128];
    int tid = threadIdx.x;
    int wg = blockIdx.x, k = blockIdx.y, bb = blockIdx.z;
    int ncol = (wg == 32) ? 1 : 2;
    tw128_init(TW, tid);
    constexpr int BR4[16] = {0,8,4,12,2,10,6,14,1,9,5,13,3,11,7,15};
    constexpr int BR3[8]  = {0,4,2,6,1,5,3,7};
    h2* q2 = fgh + (size_t)((bb*8 + k) * 65 + wg * 2) * 2048;
    #pragma unroll
    for (int it = 0; it < 16; ++it) {
        int u = tid + it * 256;
        int wl = u >> 11, rem = u & 2047;
        int h = rem >> 4, c = rem & 15;
        f2 v = (wl < ncol) ? tofloat(q2[(size_t)wl*2048 + rem]) : (f2){0.f, 0.f};
        S[h*LPITCH + 2*c + wl] = v;
    }
    __syncthreads();
    int cw = tid & 31, t = tid >> 5;   // t = 0..7 (= n2)
    f2* Scw = S + cw;
    {   // forward: FFT16 over n1, twiddle, transpose
        f2 v[16];
        #pragma unroll
        for (int j = 0; j < 16; ++j) v[j] = Scw[(8*j + t) * LPITCH];
        fft16<false>(v);
        #pragma unroll
        for (int r = 0; r < 16; ++r) {
            int k1 = BR4[r];
            Scw[(k1*8 + t) * LPITCH] = cmulF(v[r], TW[t * k1]);
        }
    }
    __syncthreads();
    {
        f2 a[8], b[8];
        int k1a = 2*t, k1b = 2*t + 1;
        #pragma unroll
        for (int n2 = 0; n2 < 8; ++n2) {
            a[n2] = Scw[(k1a*8 + n2) * LPITCH];
            b[n2] = Scw[(k1b*8 + n2) * LPITCH];
        }
        dft8<false>(a); dft8<false>(b);
        __syncthreads();
        #pragma unroll
        for (int r = 0; r < 8; ++r) {
            int k2 = BR3[r];
            Scw[(k1a + 16*k2) * LPITCH] = a[r];    // natural bin order
            Scw[(k1b + 16*k2) * LPITCH] = b[r];
        }
    }
    __syncthreads();
    // ---- gating: thread-private (bin, w) position; weights via block-uniform scalar loads ----
    {
        const float* w1r = w1 + k*256;       const float* w1i = w1 + 2048 + k*256;
        const float* w2r = w2 + k*256;       const float* w2i = w2 + 2048 + k*256;
        const float* b1r = b1 + k*16;        const float* b1i = b1 + 128 + k*16;
        const float* b2r = b2 + k*16;        const float* b2i = b2 + 128 + k*16;
        int pos = tid >> 1, wl = tid & 1;
        f2* sp = S + pos * LPITCH + wl;
        f2 v[16], o1[16], g[16];
        #pragma unroll
        for (int c = 0; c < 16; ++c) v[c] = sp[2*c];
        #pragma unroll
        for (int o = 0; o < 16; ++o) o1[o] = (f2){b1r[o], b1i[o]};
        #pragma unroll
        for (int c = 0; c < 16; ++c) {
            f2 vc = v[c];
            f2 vs = (f2){-vc.y, vc.x};
            #pragma unroll
            for (int o = 0; o < 16; ++o)
                o1[o] += vc * w1r[c*16+o] + vs * w1i[c*16+o];
        }
        #pragma unroll
        for (int o = 0; o < 16; ++o) g[o] = (f2){b2r[o], b2i[o]};
        #pragma unroll
        for (int c = 0; c < 16; ++c) {
            f2 vc = o1[c];
            f2 vs = (f2){-vc.y, vc.x};
            #pragma unroll
            for (int o = 0; o < 16; ++o)
                g[o] += vc * w2r[c*16+o] + vs * w2i[c*16+o];
        }
        #pragma unroll
        for (int o = 0; o < 16; ++o) {
            f2 gg = g[o];
            float ar = copysignf(fmaxf(fabsf(gg.x) - LAMBD, 0.f), gg.x);
            float ai = copysignf(fmaxf(fabsf(gg.y) - LAMBD, 0.f), gg.y);
            sp[2*o] = cmulF(v[o], (f2){ar, ai});   // z = g * f
        }
    }
    __syncthreads();
    {   // inverse: IDFT8 over k2, conj twiddle, transpose
        f2 a[8], b[8];
        int k1a = 2*t, k1b = 2*t + 1;
        #pragma unroll
        for (int k2 = 0; k2 < 8; ++k2) {
            a[k2] = Scw[(k1a + 16*k2) * LPITCH];
            b[k2] = Scw[(k1b + 16*k2) * LPITCH];
        }
        dft8<true>(a); dft8<true>(b);
        __syncthreads();
        #pragma unroll
        for (int r = 0; r < 8; ++r) {
            int n2 = BR3[r];
            Scw[(k1a*8 + n2) * LPITCH] = cmulC(a[r], TW[n2 * k1a]);
            Scw[(k1b*8 + n2) * LPITCH] = cmulC(b[r], TW[n2 * k1b]);
        }
    }
    __syncthreads();
    {   // IFFT16 over k1 (thread-private slots)
        f2 v[16];
        #pragma unroll
        for (int j = 0; j < 16; ++j) v[j] = Scw[(8*j + t) * LPITCH];
        fft16<true>(v);
        #pragma unroll
        for (int r = 0; r < 16; ++r)
            Scw[(8*BR4[r] + t) * LPITCH] = v[r];                       // spatial n = 8*n1 + t
    }
    __syncthreads();
    const float scale = 1.0f / 128.0f;   // full inverse scale carried here
    #pragma unroll
    for (int it = 0; it < 16; ++it) {
        int u = tid + it * 256;
        int wl = u >> 11, rem = u & 2047;
        int h = rem >> 4, c = rem & 15;
        if (wl < ncol)
            q2[(size_t)wl*2048 + rem] = tohalf(S[h*LPITCH + 2*c + wl] * scale);
    }
}

// ============ Pass 2: row irFFT (radix 16x8) + residual add into y (fp16) ============
__global__ __launch_bounds__(256) void rowifft_kernel(const h2* __restrict__ fgh,
                                                      _Float16* __restrict__ yh) {
    __shared__ f2 S[128 * LPITCH];
    __shared__ f2 TW[128];
    int tid = threadIdx.x;
    int ht = blockIdx.x, k = blockIdx.y, bb = blockIdx.z;
    tw128_init(TW, tid);
    constexpr int BR4[16] = {0,8,4,12,2,10,6,14,1,9,5,13,3,11,7,15};
    constexpr int BR3[8]  = {0,4,2,6,1,5,3,7};
    const h2* src = fgh + (size_t)((bb*8 + k) * 65) * 2048 + ht * 32;
    #pragma unroll
    for (int it = 0; it < 9; ++it) {
        int u = tid + it * 256;
        if (u < 2080) {
            int w = u >> 5, r = u & 31;
            f2 v = tofloat(src[(size_t)w * 2048 + r]);
            S[w*LPITCH + r] = v;
            if (w > 0 && w < 64) S[(128 - w)*LPITCH + r] = (f2){v.x, -v.y};  // Hermitian
        }
    }
    __syncthreads();
    int cw = tid & 31, t = tid >> 5;
    f2* Scw = S + cw;
    {   // IDFT8 over k2, conj twiddle, transpose
        f2 a[8], b[8];
        int k1a = 2*t, k1b = 2*t + 1;
        #pragma unroll
        for (int k2 = 0; k2 < 8; ++k2) {
            a[k2] = Scw[(k1a + 16*k2) * LPITCH];
            b[k2] = Scw[(k1b + 16*k2) * LPITCH];
        }
        dft8<true>(a); dft8<true>(b);
        __syncthreads();
        #pragma unroll
        for (int r = 0; r < 8; ++r) {
            int n2 = BR3[r];
            Scw[(k1a*8 + n2) * LPITCH] = cmulC(a[r], TW[n2 * k1a]);
            Scw[(k1b*8 + n2) * LPITCH] = cmulC(b[r], TW[n2 * k1b]);
        }
    }
    __syncthreads();
    {   // IFFT16 over k1 (thread-private slots), natural spatial output
        f2 v[16];
        #pragma unroll
        for (int j = 0; j < 16; ++j) v[j] = Scw[(8*j + t) * LPITCH];
        fft16<true>(v);
        #pragma unroll
        for (int r = 0; r < 16; ++r)
            Scw[(8*BR4[r] + t) * LPITCH] = v[r];
    }
    __syncthreads();
    // s = irfft + y, in place on yh (fp16 pairs); natural spatial order in S
    #pragma unroll
    for (int it = 0; it < 8; ++it) {
        int u = tid + it * 256;
        int r = u >> 6, tp = u & 63;
        int c16 = r & 15, hh = r >> 4;
        int h = ht * 2 + hh;
        size_t offp = ((size_t)(bb*128 + k*16 + c16) * 128 + h) * 64 + tp;
        h2* yp = (h2*)yh + offp;
        h2 old = *yp;
        float s0 = (float)old.x + S[(2*tp)*LPITCH + r].x;
        float s1 = (float)old.y + S[(2*tp+1)*LPITCH + r].x;
        *yp = (h2){(_Float16)s0, (_Float16)s1};
    }
}

// ================= Pass 3: bilinear 2x upsample + bias x, 8 outputs / thread =================
__global__ __launch_bounds__(256) void upsample_kernel(const _Float16* __restrict__ sh,
                                                       const float* __restrict__ x,
                                                       float* __restrict__ out) {
    int t8 = blockIdx.x * blockDim.x + threadIdx.x;  // one thread = 8 consecutive output cols
    int tJ = t8 & 31;          // output col group: J = 8*tJ
    int r  = t8 >> 5;
    int I  = r & 255;
    int bc = r >> 8;
    float syf = (float)I * 0.5f - 0.25f;
    int y0 = (int)floorf(syf);
    float fy = syf - (float)y0;
    int y1 = y0 + 1; if (y1 > 127) y1 = 127; if (y0 < 0) y0 = 0;
    const h2* r0 = (const h2*)(sh + ((size_t)bc * 128 + y0) * 128);
    const h2* r1 = (const h2*)(sh + ((size_t)bc * 128 + y1) * 128);
    int i0 = 2 * tJ;
    h2 A0 = r0[i0], A1 = r0[i0 + 1];
    h2 B0 = r1[i0], B1 = r1[i0 + 1];
    float am1 = (tJ == 0)  ? (float)A0.x : (float)r0[i0 - 1].y;
    float ap4 = (tJ == 31) ? (float)A1.y : (float)r0[i0 + 2].x;
    float bm1 = (tJ == 0)  ? (float)B0.x : (float)r1[i0 - 1].y;
    float bp4 = (tJ == 31) ? (float)B1.y : (float)r1[i0 + 2].x;
    // row-lerped source cols 4tJ-1 .. 4tJ+4
    float vm = am1 + fy * (bm1 - am1);
    float v0 = (float)A0.x + fy * ((float)B0.x - (float)A0.x);
    float v1 = (float)A0.y + fy * ((float)B0.y - (float)A0.y);
    float v2 = (float)A1.x + fy * ((float)B1.x - (float)A1.x);
    float v3 = (float)A1.y + fy * ((float)B1.y - (float)A1.y);
    float v4 = ap4 + fy * (bp4 - ap4);
    const float* xp = x + (size_t)t8 * 8;
    float4 x0 = *(const float4*)xp;
    float4 x1 = *(const float4*)(xp + 4);
    float4 o0, o1;
    o0.x = vm + 0.75f * (v0 - vm) + x0.x;
    o0.y = v0 + 0.25f * (v1 - v0) + x0.y;
    o0.z = v0 + 0.75f * (v1 - v0) + x0.z;
    o0.w = v1 + 0.25f * (v2 - v1) + x0.w;
    o1.x = v1 + 0.75f * (v2 - v1) + x1.x;
    o1.y = v2 + 0.25f * (v3 - v2) + x1.y;
    o1.z = v2 + 0.75f * (v3 - v2) + x1.z;
    o1.w = v3 + 0.25f * (v4 - v3) + x1.w;
    float* op = out + (size_t)t8 * 8;
    *(float4*)op = o0;
    *(float4*)(op + 4) = o1;
}

extern "C" void kernel_launch(void* const* d_in, const int* in_sizes, int n_in,
                              void* d_out, int out_size, void* d_ws, size_t ws_size,
                              hipStream_t stream) {
    const float* x  = (const float*)d_in[0];
    const float* w1 = (const float*)d_in[1];
    const float* b1 = (const float*)d_in[2];
    const float* w2 = (const float*)d_in[3];
    const float* b2 = (const float*)d_in[4];
    float*     out = (float*)d_out;
    _Float16*  yh  = (_Float16*)d_ws;  // 33.5 MB: pooled image, then s = irfft + y (fp16)
    h2*        fgh = (h2*)d_out;       // 34 MB transposed spectral scratch inside d_out (fp16 pairs)

    poolfft_kernel<<<dim3(64, 8, 8), 256, 0, stream>>>(x, yh, fgh);
    specfused_kernel<<<dim3(33, 8, 8), 256, 0, stream>>>(fgh, w1, b1, w2, b2);
    rowifft_kernel<<<dim3(64, 8, 8), 256, 0, stream>>>(fgh, yh);
    upsample_kernel<<<1024 * 256 * 32 / 256, 256, 0, stream>>>(yh, x, out);
}